// Round 1
// baseline (332.873 us; speedup 1.0000x reference)
//
#include <hip/hip_runtime.h>
#include <hip/hip_cooperative_groups.h>
#include <hip/hip_bf16.h>
#include <math.h>

namespace cg = cooperative_groups;

#define B_ 4
#define S_ 1024
#define H_ 512
#define NH_ 8
#define HD_ 64
#define FF_ 1024
#define E_ 4
#define L_ 4
#define NT_ 17
#define BS_ 4096
#define EPS_ 1e-5f
#define L2E_ 1.4426950408889634f
#define SCL_ 0.18033688011112042f   // 0.125 * log2(e)
#define KSPLIT_ 4

typedef __attribute__((ext_vector_type(8))) short short8;
typedef __attribute__((ext_vector_type(16))) float f32x16;
typedef float float4u __attribute__((ext_vector_type(4), aligned(4)));

__device__ inline ushort bf16_rne(float f) {
  unsigned u = __builtin_bit_cast(unsigned, f);
  u += 0x7FFFu + ((u >> 16) & 1u);
  return (ushort)(u >> 16);
}
__device__ inline unsigned pk_bf16(float a, float b) {
  return (unsigned)bf16_rne(a) | ((unsigned)bf16_rne(b) << 16);
}
// fast pack: round-half-away + v_perm_b32 (3 VALU ops)
__device__ inline unsigned pk2(float a, float b) {
  unsigned ua = __builtin_bit_cast(unsigned, a) + 0x8000u;
  unsigned ub = __builtin_bit_cast(unsigned, b) + 0x8000u;
  return __builtin_amdgcn_perm(ub, ua, 0x07060302u);
}
__device__ inline float ubf2f(ushort u) {
  return __builtin_bit_cast(float, ((unsigned)u) << 16);
}

// ===========================================================================
// R18: FUSED COOPERATIVE KERNEL.
// Evidence: top-5 rocprof dispatches are all 42us harness fills => every one
// of our 13 kernels is <42us; bottom-up work models sum to ~150us vs 332us
// measured => ~12-15us per kernel boundary (launch+ramp+drain+round tails).
// Fix: 1 cooperative launch, 12 grid.sync()s. grid 512x256, 2 blocks/CU
// (LDS 72KiB union), all phases remapped onto 512 blocks. attn runs slots
// bid and bid+512 (same bh/qt => Qf hoisted across both j-chunks).
// Fallback: original 13-launch path if cooperative launch unavailable.
// ===========================================================================

struct FP {
  const int* patches; const int* mask;
  const float* emb; const float* relemb; const float* Wqkv;
  const float* Wi; const float* bi; const float* g1; const float* b1n;
  const float* bqkv; const float* Wo; const float* bo;
  const float* g2; const float* b2n;
  const float* Wf1; const float* bf1; const float* Wf2; const float* bf2;
  const float* Wout; const float* bout;
  float* x; float* T; float* negT; float* AOp; float* lpart; float* out;
  ushort* xnbf; ushort* Wt; ushort* qf; ushort* kf; ushort* vf;
};

__global__ __launch_bounds__(256, 2) void k_fused(FP p) {
  __shared__ union {
    struct { ushort At[2][128][72]; ushort Bt[2][128][72]; } g;  // qkv: 73728 B
    struct { ushort Tr[64][72]; } pr;                            // pre transpose
    struct { ushort Pt[4][32][72]; } a;                          // attn P tiles
  } sm;
  const int bid = blockIdx.x;
  const int t = threadIdx.x;
  cg::grid_group grid = cg::this_grid();

  // local __restrict__ views (FP members alias-opaque otherwise)
  const int* __restrict__ patches = p.patches;
  const int* __restrict__ mask = p.mask;
  const float* __restrict__ emb = p.emb;
  const float* __restrict__ relemb = p.relemb;
  const float* __restrict__ Wqkv = p.Wqkv;
  const float* __restrict__ WiB = p.Wi;
  const float* __restrict__ biB = p.bi;
  const float* __restrict__ g1B = p.g1;
  const float* __restrict__ b1nB = p.b1n;
  const float* __restrict__ bqkvB = p.bqkv;
  const float* __restrict__ WoB = p.Wo;
  const float* __restrict__ boB = p.bo;
  const float* __restrict__ g2B = p.g2;
  const float* __restrict__ b2nB = p.b2n;
  const float* __restrict__ Wf1B = p.Wf1;
  const float* __restrict__ bf1B = p.bf1;
  const float* __restrict__ Wf2B = p.Wf2;
  const float* __restrict__ bf2B = p.bf2;
  const float* __restrict__ Wout = p.Wout;
  const float* __restrict__ bout = p.bout;
  float* __restrict__ x = p.x;
  float* __restrict__ T = p.T;
  float* __restrict__ negT = p.negT;
  float* __restrict__ AOp = p.AOp;
  float* __restrict__ lpart = p.lpart;
  float* __restrict__ out = p.out;
  ushort* __restrict__ xnbf = p.xnbf;
  ushort* __restrict__ Wt = p.Wt;
  ushort* __restrict__ qf = p.qf;
  ushort* __restrict__ kf = p.kf;
  ushort* __restrict__ vf = p.vf;

  // ================= phase 0: prologue (was k_pre, 1841 virtual blocks) ====
#pragma unroll 1
  for (int vb = bid; vb < 1841; vb += 512) {
    if (vb < 768) {
      ushort(&Tr)[64][72] = sm.pr.Tr;
      int l = vb / 192, rem = vb % 192;
      int k0 = (rem / 24) * 64, n0 = (rem % 24) * 64;
      const float* src = Wqkv + (size_t)l * 512 * 1536;
      int row = t >> 4, c4 = (t & 15) * 4;
#pragma unroll
      for (int rr = 0; rr < 4; rr++) {
        int k = rr * 16 + row;
        float4 v = *(const float4*)(src + (size_t)(k0 + k) * 1536 + n0 + c4);
        Tr[c4 + 0][k] = bf16_rne(v.x);
        Tr[c4 + 1][k] = bf16_rne(v.y);
        Tr[c4 + 2][k] = bf16_rne(v.z);
        Tr[c4 + 3][k] = bf16_rne(v.w);
      }
      __syncthreads();
      int nrow = t >> 2, kc = (t & 3) * 16;
      ushort* dst = Wt + ((size_t)(l * 1536 + n0 + nrow)) * 512 + k0 + kc;
      *(uint4*)dst = *(uint4*)&Tr[nrow][kc];
      *(uint4*)(dst + 8) = *(uint4*)&Tr[nrow][kc + 8];
      __syncthreads();  // Tr reused by next vb iteration of this block
    } else if (vb < 817) {
      int gid = (vb - 768) * 256 + t;
      if (gid < BS_) {
        int mk = mask[gid];
        int row = mk ? (NT_ - 1) : patches[gid];
        ((float4*)x)[gid] = ((const float4*)emb)[row];
        negT[gid] = mk ? -1e30f : 0.f;
      } else {
        int idx = gid - BS_;
        if (idx < L_ * 2112) {
          int l = idx / 2112, j = idx - l * 2112;
          int c = 1086 - j;
          c = c < 0 ? 0 : (c > 62 ? 62 : c);
          const float* src = relemb + (size_t)(l * 63 + c) * 64;
          float s = 0.f;
#pragma unroll
          for (int d = 0; d < 64; d++) s += src[d];
          T[idx] = s * L2E_;
        }
      }
    } else {
      int token = (vb - 817) * 4 + (t >> 6);
      int lane = t & 63;
      int mk = mask[token];
      int row = mk ? (NT_ - 1) : patches[token];
      float4 e = ((const float4*)emb)[row];
      float xp[8];
      float s = 0.f, qs = 0.f;
#pragma unroll
      for (int k = 0; k < 8; k++) {
        int jj = 64 * k + lane;
        float v = biB[jj] + e.x * WiB[jj] + e.y * WiB[H_ + jj] + e.z * WiB[2 * H_ + jj] + e.w * WiB[3 * H_ + jj];
        xp[k] = v; s += v; qs += v * v;
      }
#pragma unroll
      for (int o = 1; o < 64; o <<= 1) { s += __shfl_xor(s, o); qs += __shfl_xor(qs, o); }
      float mean = s * (1.f / (float)H_);
      float var = qs * (1.f / (float)H_) - mean * mean;
      float rs = rsqrtf(var + EPS_);
#pragma unroll
      for (int k = 0; k < 8; k++) {
        int jj = 64 * k + lane;
        xnbf[token * H_ + jj] = bf16_rne((xp[k] - mean) * rs * g1B[jj] + b1nB[jj]);
      }
    }
  }
  grid.sync();

#pragma unroll 1
  for (int l = 0; l < L_; l++) {
    // ---------------- qkv (blocks 0..383) ----------------
    if (bid < 384) {
      ushort(&At)[2][128][72] = sm.g.At;
      ushort(&Bt)[2][128][72] = sm.g.Bt;
      const ushort* Aq = xnbf;
      const ushort* Wtl = Wt + (size_t)l * 1536 * 512;
      const float* biasq = bqkvB + l * 3 * H_;
      int n0 = (bid % 12) * 128, m0 = (bid / 12) * 128;
      bool trq = (n0 < 1024);
      int w = t >> 6, lq = t & 31, hh = (t >> 5) & 1;
      int wm = (w & 1) * 64, wn = (w >> 1) * 64;
      f32x16 acc[2][2];
#pragma unroll
      for (int mt = 0; mt < 2; mt++)
#pragma unroll
        for (int nt = 0; nt < 2; nt++)
#pragma unroll
          for (int i = 0; i < 16; i++) acc[mt][nt][i] = 0.f;
      uint4 ar[4], br[4];

#define FQLOADREGS(k0_)                                                         \
  {                                                                             \
    _Pragma("unroll") for (int jx = 0; jx < 4; jx++) {                          \
      int idl = 256 * jx + t;                                                   \
      int row = idl >> 3, u = idl & 7;                                          \
      ar[jx] = *(const uint4*)(Aq + (size_t)(m0 + row) * 512 + (k0_) + u * 8);  \
      br[jx] = *(const uint4*)(Wtl + (size_t)(n0 + row) * 512 + (k0_) + u * 8); \
    }                                                                           \
  }
#define FQWRITELDS(buf_)                                                        \
  {                                                                             \
    _Pragma("unroll") for (int jx = 0; jx < 4; jx++) {                          \
      int idl = 256 * jx + t;                                                   \
      int row = idl >> 3, u = idl & 7;                                          \
      *(uint4*)&At[buf_][row][u * 8] = ar[jx];                                  \
      *(uint4*)&Bt[buf_][row][u * 8] = br[jx];                                  \
    }                                                                           \
  }
      FQLOADREGS(0);
      FQWRITELDS(0);
      __syncthreads();
      for (int it = 0; it < 8; it++) {
        int buf = it & 1;
        if (it < 7) { FQLOADREGS((it + 1) * 64); }
#pragma unroll
        for (int kc = 0; kc < 4; kc++) {
          short8 af[2], bfr[2];
#pragma unroll
          for (int mt = 0; mt < 2; mt++) af[mt] = *(const short8*)&At[buf][wm + mt * 32 + lq][kc * 16 + hh * 8];
#pragma unroll
          for (int nt = 0; nt < 2; nt++) bfr[nt] = *(const short8*)&Bt[buf][wn + nt * 32 + lq][kc * 16 + hh * 8];
#pragma unroll
          for (int mt = 0; mt < 2; mt++)
#pragma unroll
            for (int nt = 0; nt < 2; nt++) {
              if (trq)
                acc[mt][nt] = __builtin_amdgcn_mfma_f32_32x32x16_bf16(bfr[nt], af[mt], acc[mt][nt], 0, 0, 0);
              else
                acc[mt][nt] = __builtin_amdgcn_mfma_f32_32x32x16_bf16(af[mt], bfr[nt], acc[mt][nt], 0, 0, 0);
            }
        }
        if (it < 7) {
          FQWRITELDS(buf ^ 1);
          __syncthreads();
        }
      }
#undef FQLOADREGS
#undef FQWRITELDS

      if (trq) {
#pragma unroll
        for (int mt = 0; mt < 2; mt++) {
          int token = m0 + wm + mt * 32 + lq;
          int bb = token >> 10, sr = token & 1023;
          int qt = sr >> 5, lqp = sr & 31;
#pragma unroll
          for (int nt = 0; nt < 2; nt++) {
            int nn = n0 + wn + nt * 32;
            int nloc = (nn < 512) ? nn : nn - 512;
            ushort* dst = (nn < 512) ? qf : kf;
            int hd = nloc >> 6;
            int bh = bb * 8 + hd;
            size_t fragbase = ((size_t)(bh * 32 + qt)) * 4 * 512;
#pragma unroll
            for (int rg = 0; rg < 4; rg++) {
              int nbase = nn + rg * 8 + hh * 4;
              float4 bv = *(const float4*)(biasq + nbase);
              float v0 = acc[mt][nt][rg * 4 + 0] + bv.x;
              float v1 = acc[mt][nt][rg * 4 + 1] + bv.y;
              float v2 = acc[mt][nt][rg * 4 + 2] + bv.z;
              float v3 = acc[mt][nt][rg * 4 + 3] + bv.w;
              int d0 = (nloc & 63) + rg * 8 + hh * 4;
              size_t addr = fragbase + (size_t)(d0 >> 4) * 512 +
                            (size_t)(((d0 >> 3) & 1) * 32 + lqp) * 8 + (d0 & 7);
              *(uint2*)(dst + addr) = make_uint2(pk_bf16(v0, v1), pk_bf16(v2, v3));
            }
          }
        }
      } else {
#pragma unroll
        for (int nt = 0; nt < 2; nt++) {
          int n = n0 + wn + nt * 32 + lq;
          int nloc = n - 1024;
          int hd = nloc >> 6, d = nloc & 63;
          float bb_ = biasq[n];
#pragma unroll
          for (int mt = 0; mt < 2; mt++) {
#pragma unroll
            for (int rg = 0; rg < 4; rg++) {
              int tb = m0 + wm + mt * 32 + rg * 8 + hh * 4;
              int bb = tb >> 10, sr = tb & 1023;
              int bh = bb * 8 + hd;
              float v0 = acc[mt][nt][rg * 4 + 0] + bb_;
              float v1 = acc[mt][nt][rg * 4 + 1] + bb_;
              float v2 = acc[mt][nt][rg * 4 + 2] + bb_;
              float v3 = acc[mt][nt][rg * 4 + 3] + bb_;
              size_t addr = ((size_t)((bh * 2 + (d >> 5)) * 64 + (sr >> 4))) * 512 +
                            (size_t)(((sr >> 3) & 1) * 32 + (d & 31)) * 8 + (sr & 7);
              *(uint2*)(vf + addr) = make_uint2(pk_bf16(v0, v1), pk_bf16(v2, v3));
            }
          }
        }
      }
    }
    grid.sync();

    // ---------------- attn: slots bid and bid+512 (same bh/qt => Qf reuse) --
    {
      const float* Tl = T + l * 2112;
      const float* Wol = WoB + (size_t)l * H_ * E_;
      ushort(&Pt)[4][32][72] = sm.a.Pt;
      int w = t >> 6, lane = t & 63;
      int lq = lane & 31, hh = lane >> 5;
      int bh = bid & 31;
      int slot = bid >> 5;           // [0,16)
      int qtg = slot & 7, j0 = slot >> 3;   // j0 in {0,1}; second pass j0+2
      int b = bh >> 3, head = bh & 7;
      int qt = qtg * 4 + w;
      int q = qt * 32 + lq;

      const ushort* qbase = qf + ((size_t)(bh * 32 + qt)) * 2048 + lane * 8;
      short8 Qf[4];
#pragma unroll
      for (int c = 0; c < 4; c++) Qf[c] = *(const short8*)(qbase + c * 512);

      float Tlo = Tl[1086];
      float Thi = Tl[1024];

#pragma unroll 1
      for (int jj = 0; jj < 2; jj++) {
        int j = j0 + 2 * jj;
        int kstart = j * 256;
        float l_run = 0.f;
        f32x16 Ot[2];
#pragma unroll
        for (int dt = 0; dt < 2; dt++)
#pragma unroll
          for (int i = 0; i < 16; i++) Ot[dt][i] = 0.f;

        for (int it = 0; it < 4; it++) {
          int k0 = kstart + it * 64;
          short8 Kb[2][4];
#pragma unroll
          for (int st = 0; st < 2; st++) {
            const ushort* kb = kf + ((size_t)(bh * 32 + (k0 >> 5) + st)) * 2048 + lane * 8;
#pragma unroll
            for (int c = 0; c < 4; c++) Kb[st][c] = *(const short8*)(kb + c * 512);
          }
          short8 Vb[2][4];
#pragma unroll
          for (int dt = 0; dt < 2; dt++) {
            const ushort* vbp = vf + ((size_t)((bh * 2 + dt) * 64 + (k0 >> 4))) * 512 + lane * 8;
#pragma unroll
            for (int c = 0; c < 4; c++) Vb[dt][c] = *(const short8*)(vbp + c * 512);
          }
          // ---- S^T ----
          f32x16 sa[2];
#pragma unroll
          for (int st = 0; st < 2; st++) {
            f32x16 a;
#pragma unroll
            for (int i = 0; i < 16; i++) a[i] = 0.f;
#pragma unroll
            for (int c = 0; c < 4; c++)
              a = __builtin_amdgcn_mfma_f32_32x32x16_bf16(Kb[st][c], Qf[c], a, 0, 0, 0);
            sa[st] = a;
          }
          // ---- softmax: band-specialized ----
#pragma unroll
          for (int st = 0; st < 2; st++) {
            int kt0 = k0 + st * 32;
            int delta = kt0 - qt * 32;
            if (delta >= 64 || delta <= -64) {
              float bconst = (delta >= 64) ? Tlo : Thi;
#pragma unroll
              for (int rg = 0; rg < 4; rg++) {
                int krun = kt0 + rg * 8 + hh * 4;
                float4 nv = *(const float4*)(negT + b * S_ + krun);
                float p0 = exp2f(fmaf(sa[st][rg * 4 + 0], SCL_, bconst + nv.x));
                float p1 = exp2f(fmaf(sa[st][rg * 4 + 1], SCL_, bconst + nv.y));
                float p2 = exp2f(fmaf(sa[st][rg * 4 + 2], SCL_, bconst + nv.z));
                float p3 = exp2f(fmaf(sa[st][rg * 4 + 3], SCL_, bconst + nv.w));
                l_run += (p0 + p1) + (p2 + p3);
                *(uint2*)&Pt[w][lq][st * 32 + rg * 8 + hh * 4] = make_uint2(pk2(p0, p1), pk2(p2, p3));
              }
            } else {
#pragma unroll
              for (int rg = 0; rg < 4; rg++) {
                int krun = kt0 + rg * 8 + hh * 4;
                float4u bv = *(const float4u*)(Tl + (krun - q + 31 + 1024));
                float4 nv = *(const float4*)(negT + b * S_ + krun);
                float pp[4];
#pragma unroll
                for (int i = 0; i < 4; i++) {
                  float nvi = (i == 0) ? nv.x : (i == 1) ? nv.y : (i == 2) ? nv.z : nv.w;
                  float t0 = (krun + i == q) ? bv[i] : (bv[i] + nvi);
                  pp[i] = exp2f(fmaf(sa[st][rg * 4 + i], SCL_, t0));
                  l_run += pp[i];
                }
                *(uint2*)&Pt[w][lq][st * 32 + rg * 8 + hh * 4] = make_uint2(pk2(pp[0], pp[1]), pk2(pp[2], pp[3]));
              }
            }
          }
          // ---- O^T += V^T . P ----
          short8 Pf[4];
#pragma unroll
          for (int c = 0; c < 4; c++) Pf[c] = *(const short8*)&Pt[w][lq][c * 16 + hh * 8];
#pragma unroll
          for (int dt = 0; dt < 2; dt++)
#pragma unroll
            for (int c = 0; c < 4; c++)
              Ot[dt] = __builtin_amdgcn_mfma_f32_32x32x16_bf16(Vb[dt][c], Pf[c], Ot[dt], 0, 0, 0);
        }
        // ---- epilogue: project through Wo[head], store private j-slot partial
        const float* woh = Wol + head * 64 * 4;
        float pe0 = 0.f, pe1 = 0.f, pe2 = 0.f, pe3 = 0.f;
#pragma unroll
        for (int dt = 0; dt < 2; dt++)
#pragma unroll
          for (int rg = 0; rg < 4; rg++)
#pragma unroll
            for (int i = 0; i < 4; i++) {
              int d = dt * 32 + rg * 8 + hh * 4 + i;
              float4 wv = *(const float4*)(woh + d * 4);
              float o = Ot[dt][rg * 4 + i];
              pe0 = fmaf(o, wv.x, pe0);
              pe1 = fmaf(o, wv.y, pe1);
              pe2 = fmaf(o, wv.z, pe2);
              pe3 = fmaf(o, wv.w, pe3);
            }
        pe0 += __shfl_xor(pe0, 32);
        pe1 += __shfl_xor(pe1, 32);
        pe2 += __shfl_xor(pe2, 32);
        pe3 += __shfl_xor(pe3, 32);
        float l_tot = l_run + __shfl_xor(l_run, 32);
        if (hh == 0) {
          float* ao = AOp + (size_t)j * (BS_ * NH_ * 4) + ((size_t)(b * S_ + q) * NH_ + head) * 4;
          *(float4*)ao = make_float4(pe0, pe1, pe2, pe3);
          lpart[((size_t)j * 32 + bh) * S_ + q] = l_tot;
        }
      }
    }
    grid.sync();

    // ---------------- resffn: 2 token-groups per block ----------------
    {
      const float* bo_l = boB + l * E_;
      const float* g2_l = g2B + l * E_;
      const float* b2n_l = b2nB + l * E_;
      const float* Wf1_l = Wf1B + (size_t)l * E_ * FF_;
      const float* bf1_l = bf1B + (size_t)l * FF_;
      const float* Wf2_l = Wf2B + (size_t)l * FF_ * E_;
      const float* bf2_l = bf2B + l * E_;
      const float* Wi_n = WiB + (size_t)(l + 1) * E_ * H_;
      const float* bi_n = biB + (size_t)(l + 1) * H_;
      const float* g1_n = g1B + (size_t)(l + 1) * H_;
      const float* b1n_n = b1nB + (size_t)(l + 1) * H_;
      int lane = t & 63;
      int h = lane & 7;
#pragma unroll 1
      for (int gg = 0; gg < 2; gg++) {
        int tok = (bid * 2 + gg) * 4 + (t >> 6);
        int bq = tok >> 10, qq = tok & 1023;
        int lidx = (bq * 8 + h) * 1024 + qq;
        float ls = lpart[lidx] + lpart[lidx + 32768] + lpart[lidx + 65536] + lpart[lidx + 98304];
        float inv = 1.f / ls;
        size_t abase = ((size_t)tok * 8 + h) * 4;
        float4 v0 = *(const float4*)(AOp + abase);
        float4 v1 = *(const float4*)(AOp + abase + 131072);
        float4 v2 = *(const float4*)(AOp + abase + 262144);
        float4 v3 = *(const float4*)(AOp + abase + 393216);
        float r0 = (v0.x + v1.x + v2.x + v3.x) * inv;
        float r1 = (v0.y + v1.y + v2.y + v3.y) * inv;
        float r2 = (v0.z + v1.z + v2.z + v3.z) * inv;
        float r3 = (v0.w + v1.w + v2.w + v3.w) * inv;
#pragma unroll
        for (int o = 1; o < 8; o <<= 1) {
          r0 += __shfl_xor(r0, o); r1 += __shfl_xor(r1, o);
          r2 += __shfl_xor(r2, o); r3 += __shfl_xor(r3, o);
        }
        float4 xo = *(const float4*)&x[tok * 4];
        float x0 = xo.x + r0 + bo_l[0];
        float x1 = xo.y + r1 + bo_l[1];
        float x2 = xo.z + r2 + bo_l[2];
        float x3 = xo.w + r3 + bo_l[3];
        float mn = 0.25f * (x0 + x1 + x2 + x3);
        float d0 = x0 - mn, d1 = x1 - mn, d2 = x2 - mn, d3 = x3 - mn;
        float var = 0.25f * (d0 * d0 + d1 * d1 + d2 * d2 + d3 * d3);
        float rs = rsqrtf(var + EPS_);
        float l0 = d0 * rs * g2_l[0] + b2n_l[0];
        float l1 = d1 * rs * g2_l[1] + b2n_l[1];
        float l2 = d2 * rs * g2_l[2] + b2n_l[2];
        float l3 = d3 * rs * g2_l[3] + b2n_l[3];
        float f0 = 0, f1 = 0, f2 = 0, f3 = 0;
#pragma unroll
        for (int f4 = 0; f4 < FF_ / 64; f4++) {
          int f = lane + f4 * 64;
          float hv = bf1_l[f] + l0 * Wf1_l[f] + l1 * Wf1_l[FF_ + f] + l2 * Wf1_l[2 * FF_ + f] + l3 * Wf1_l[3 * FF_ + f];
          hv = fmaxf(hv, 0.f);
          float4 w2 = *(const float4*)&Wf2_l[f * 4];
          f0 += hv * w2.x; f1 += hv * w2.y; f2 += hv * w2.z; f3 += hv * w2.w;
        }
#pragma unroll
        for (int o = 1; o < 64; o <<= 1) {
          f0 += __shfl_xor(f0, o); f1 += __shfl_xor(f1, o);
          f2 += __shfl_xor(f2, o); f3 += __shfl_xor(f3, o);
        }
        x0 += f0 + bf2_l[0]; x1 += f1 + bf2_l[1]; x2 += f2 + bf2_l[2]; x3 += f3 + bf2_l[3];
        if (l == L_ - 1) {
          if (lane < NT_)
            out[tok * NT_ + lane] = bout[lane] + x0 * Wout[lane] + x1 * Wout[NT_ + lane] +
                                    x2 * Wout[2 * NT_ + lane] + x3 * Wout[3 * NT_ + lane];
        } else {
          if (lane == 0) *(float4*)&x[tok * 4] = make_float4(x0, x1, x2, x3);
          float xp[8];
          float s = 0.f, qs = 0.f;
#pragma unroll
          for (int k = 0; k < 8; k++) {
            int jj = 64 * k + lane;
            float v = bi_n[jj] + x0 * Wi_n[jj] + x1 * Wi_n[H_ + jj] + x2 * Wi_n[2 * H_ + jj] + x3 * Wi_n[3 * H_ + jj];
            xp[k] = v;
            s += v;
            qs += v * v;
          }
#pragma unroll
          for (int o = 1; o < 64; o <<= 1) {
            s += __shfl_xor(s, o);
            qs += __shfl_xor(qs, o);
          }
          float mean = s * (1.f / (float)H_);
          float var1 = qs * (1.f / (float)H_) - mean * mean;
          float rs1 = rsqrtf(var1 + EPS_);
#pragma unroll
          for (int k = 0; k < 8; k++) {
            int jj = 64 * k + lane;
            float v = (xp[k] - mean) * rs1 * g1_n[jj] + b1n_n[jj];
            xnbf[tok * H_ + jj] = bf16_rne(v);
          }
        }
      }
    }
    if (l < L_ - 1) grid.sync();
  }
}

// ===========================================================================
// Fallback path: original 13-launch pipeline (verified at 331us) -- used only
// if cooperative launch is unavailable.
// ===========================================================================

__global__ __launch_bounds__(256) void k_pre(const int* __restrict__ patches,
                                             const int* __restrict__ mask,
                                             const float* __restrict__ emb,
                                             const float* __restrict__ relemb,
                                             const float* __restrict__ W,
                                             const float* __restrict__ Wi,
                                             const float* __restrict__ bi,
                                             const float* __restrict__ g1,
                                             const float* __restrict__ b1n,
                                             float* __restrict__ x,
                                             float* __restrict__ T,
                                             float* __restrict__ negT,
                                             ushort* __restrict__ Wt,
                                             ushort* __restrict__ xnbf) {
  __shared__ ushort Tr[64][72];
  int bid = blockIdx.x, t = threadIdx.x;
  if (bid < 768) {
    int l = bid / 192, rem = bid % 192;
    int k0 = (rem / 24) * 64, n0 = (rem % 24) * 64;
    const float* src = W + (size_t)l * 512 * 1536;
    int row = t >> 4, c4 = (t & 15) * 4;
#pragma unroll
    for (int rr = 0; rr < 4; rr++) {
      int k = rr * 16 + row;
      float4 v = *(const float4*)(src + (size_t)(k0 + k) * 1536 + n0 + c4);
      Tr[c4 + 0][k] = bf16_rne(v.x);
      Tr[c4 + 1][k] = bf16_rne(v.y);
      Tr[c4 + 2][k] = bf16_rne(v.z);
      Tr[c4 + 3][k] = bf16_rne(v.w);
    }
    __syncthreads();
    int nrow = t >> 2, kc = (t & 3) * 16;
    ushort* dst = Wt + ((size_t)(l * 1536 + n0 + nrow)) * 512 + k0 + kc;
    *(uint4*)dst = *(uint4*)&Tr[nrow][kc];
    *(uint4*)(dst + 8) = *(uint4*)&Tr[nrow][kc + 8];
  } else if (bid < 817) {
    int gid = (bid - 768) * 256 + t;
    if (gid < BS_) {
      int mk = mask[gid];
      int row = mk ? (NT_ - 1) : patches[gid];
      ((float4*)x)[gid] = ((const float4*)emb)[row];
      negT[gid] = mk ? -1e30f : 0.f;
    } else {
      int idx = gid - BS_;
      if (idx < L_ * 2112) {
        int l = idx / 2112, j = idx - l * 2112;
        int c = 1086 - j;
        c = c < 0 ? 0 : (c > 62 ? 62 : c);
        const float* src = relemb + (size_t)(l * 63 + c) * 64;
        float s = 0.f;
#pragma unroll
        for (int d = 0; d < 64; d++) s += src[d];
        T[idx] = s * L2E_;
      }
    }
  } else {
    int token = (bid - 817) * 4 + (t >> 6);
    int lane = t & 63;
    int mk = mask[token];
    int row = mk ? (NT_ - 1) : patches[token];
    float4 e = ((const float4*)emb)[row];
    float xp[8];
    float s = 0.f, qs = 0.f;
#pragma unroll
    for (int k = 0; k < 8; k++) {
      int jj = 64 * k + lane;
      float v = bi[jj] + e.x * Wi[jj] + e.y * Wi[H_ + jj] + e.z * Wi[2 * H_ + jj] + e.w * Wi[3 * H_ + jj];
      xp[k] = v; s += v; qs += v * v;
    }
#pragma unroll
    for (int o = 1; o < 64; o <<= 1) { s += __shfl_xor(s, o); qs += __shfl_xor(qs, o); }
    float mean = s * (1.f / (float)H_);
    float var = qs * (1.f / (float)H_) - mean * mean;
    float rs = rsqrtf(var + EPS_);
#pragma unroll
    for (int k = 0; k < 8; k++) {
      int jj = 64 * k + lane;
      xnbf[token * H_ + jj] = bf16_rne((xp[k] - mean) * rs * g1[jj] + b1n[jj]);
    }
  }
}

__global__ __launch_bounds__(256, 2) void k_qkv(const ushort* __restrict__ A,
                                                const ushort* __restrict__ Wt,
                                                const float* __restrict__ bias,
                                                ushort* __restrict__ qf,
                                                ushort* __restrict__ kf,
                                                ushort* __restrict__ vf) {
  __shared__ ushort At[2][128][72];
  __shared__ ushort Bt[2][128][72];
  int t = threadIdx.x;
  int n0 = blockIdx.x * 128, m0 = blockIdx.y * 128;
  bool tr = (n0 < 1024);
  int w = t >> 6, lq = t & 31, hh = (t >> 5) & 1;
  int wm = (w & 1) * 64, wn = (w >> 1) * 64;
  f32x16 acc[2][2];
#pragma unroll
  for (int mt = 0; mt < 2; mt++)
#pragma unroll
    for (int nt = 0; nt < 2; nt++)
#pragma unroll
      for (int i = 0; i < 16; i++) acc[mt][nt][i] = 0.f;

  uint4 ar[4], br[4];

#define QLOADREGS(k0_)                                                         \
  {                                                                            \
    _Pragma("unroll") for (int j = 0; j < 4; j++) {                            \
      int idl = 256 * j + t;                                                   \
      int row = idl >> 3, u = idl & 7;                                         \
      ar[j] = *(const uint4*)(A + (size_t)(m0 + row) * 512 + (k0_) + u * 8);   \
      br[j] = *(const uint4*)(Wt + (size_t)(n0 + row) * 512 + (k0_) + u * 8);  \
    }                                                                          \
  }
#define QWRITELDS(buf_)                                                        \
  {                                                                            \
    _Pragma("unroll") for (int j = 0; j < 4; j++) {                            \
      int idl = 256 * j + t;                                                   \
      int row = idl >> 3, u = idl & 7;                                         \
      *(uint4*)&At[buf_][row][u * 8] = ar[j];                                  \
      *(uint4*)&Bt[buf_][row][u * 8] = br[j];                                  \
    }                                                                          \
  }

  QLOADREGS(0);
  QWRITELDS(0);
  __syncthreads();

  for (int it = 0; it < 8; it++) {
    int buf = it & 1;
    if (it < 7) { QLOADREGS((it + 1) * 64); }
#pragma unroll
    for (int kc = 0; kc < 4; kc++) {
      short8 af[2], bf[2];
#pragma unroll
      for (int mt = 0; mt < 2; mt++) af[mt] = *(const short8*)&At[buf][wm + mt * 32 + lq][kc * 16 + hh * 8];
#pragma unroll
      for (int nt = 0; nt < 2; nt++) bf[nt] = *(const short8*)&Bt[buf][wn + nt * 32 + lq][kc * 16 + hh * 8];
#pragma unroll
      for (int mt = 0; mt < 2; mt++)
#pragma unroll
        for (int nt = 0; nt < 2; nt++) {
          if (tr)
            acc[mt][nt] = __builtin_amdgcn_mfma_f32_32x32x16_bf16(bf[nt], af[mt], acc[mt][nt], 0, 0, 0);
          else
            acc[mt][nt] = __builtin_amdgcn_mfma_f32_32x32x16_bf16(af[mt], bf[nt], acc[mt][nt], 0, 0, 0);
        }
    }
    if (it < 7) {
      QWRITELDS(buf ^ 1);
      __syncthreads();
    }
  }
#undef QLOADREGS
#undef QWRITELDS

  if (tr) {
#pragma unroll
    for (int mt = 0; mt < 2; mt++) {
      int token = m0 + wm + mt * 32 + lq;
      int bb = token >> 10, sr = token & 1023;
      int qt = sr >> 5, lqp = sr & 31;
#pragma unroll
      for (int nt = 0; nt < 2; nt++) {
        int nn = n0 + wn + nt * 32;
        int nloc = (nn < 512) ? nn : nn - 512;
        ushort* dst = (nn < 512) ? qf : kf;
        int hd = nloc >> 6;
        int bh = bb * 8 + hd;
        size_t fragbase = ((size_t)(bh * 32 + qt)) * 4 * 512;
#pragma unroll
        for (int rg = 0; rg < 4; rg++) {
          int nbase = nn + rg * 8 + hh * 4;
          float4 bv = *(const float4*)(bias + nbase);
          float v0 = acc[mt][nt][rg * 4 + 0] + bv.x;
          float v1 = acc[mt][nt][rg * 4 + 1] + bv.y;
          float v2 = acc[mt][nt][rg * 4 + 2] + bv.z;
          float v3 = acc[mt][nt][rg * 4 + 3] + bv.w;
          int d0 = (nloc & 63) + rg * 8 + hh * 4;
          size_t addr = fragbase + (size_t)(d0 >> 4) * 512 +
                        (size_t)(((d0 >> 3) & 1) * 32 + lqp) * 8 + (d0 & 7);
          *(uint2*)(dst + addr) = make_uint2(pk_bf16(v0, v1), pk_bf16(v2, v3));
        }
      }
    }
  } else {
#pragma unroll
    for (int nt = 0; nt < 2; nt++) {
      int n = n0 + wn + nt * 32 + lq;
      int nloc = n - 1024;
      int hd = nloc >> 6, d = nloc & 63;
      float bb_ = bias[n];
#pragma unroll
      for (int mt = 0; mt < 2; mt++) {
#pragma unroll
        for (int rg = 0; rg < 4; rg++) {
          int tb = m0 + wm + mt * 32 + rg * 8 + hh * 4;
          int bb = tb >> 10, sr = tb & 1023;
          int bh = bb * 8 + hd;
          float v0 = acc[mt][nt][rg * 4 + 0] + bb_;
          float v1 = acc[mt][nt][rg * 4 + 1] + bb_;
          float v2 = acc[mt][nt][rg * 4 + 2] + bb_;
          float v3 = acc[mt][nt][rg * 4 + 3] + bb_;
          size_t addr = ((size_t)((bh * 2 + (d >> 5)) * 64 + (sr >> 4))) * 512 +
                        (size_t)(((sr >> 3) & 1) * 32 + (d & 31)) * 8 + (sr & 7);
          *(uint2*)(vf + addr) = make_uint2(pk_bf16(v0, v1), pk_bf16(v2, v3));
        }
      }
    }
  }
}

__global__ __launch_bounds__(256, 3) void k_attn(const ushort* __restrict__ qf,
                                                 const ushort* __restrict__ kf,
                                                 const ushort* __restrict__ vf,
                                                 const float* __restrict__ Tl,
                                                 const float* __restrict__ negT,
                                                 const float* __restrict__ Wol,
                                                 float* __restrict__ AOp,
                                                 float* __restrict__ lpart) {
  __shared__ ushort Pt[4][32][72];
  int t = threadIdx.x;
  int w = t >> 6, lane = t & 63;
  int lq = lane & 31, hh = lane >> 5;
  int id = blockIdx.x;
  int bh = id & 31;
  int slot = id >> 5;
  int qtg = slot & 7, j = slot >> 3;
  int b = bh >> 3, head = bh & 7;
  int qt = qtg * 4 + w;
  int q = qt * 32 + lq;
  int kstart = j * 256;

  const ushort* qbase = qf + ((size_t)(bh * 32 + qt)) * 2048 + lane * 8;
  short8 Qf[4];
#pragma unroll
  for (int c = 0; c < 4; c++) Qf[c] = *(const short8*)(qbase + c * 512);

  float Tlo = Tl[1086];
  float Thi = Tl[1024];

  float l_run = 0.f;
  f32x16 Ot[2];
#pragma unroll
  for (int dt = 0; dt < 2; dt++)
#pragma unroll
    for (int i = 0; i < 16; i++) Ot[dt][i] = 0.f;

  for (int it = 0; it < 4; it++) {
    int k0 = kstart + it * 64;
    short8 Kb[2][4];
#pragma unroll
    for (int st = 0; st < 2; st++) {
      const ushort* kb = kf + ((size_t)(bh * 32 + (k0 >> 5) + st)) * 2048 + lane * 8;
#pragma unroll
      for (int c = 0; c < 4; c++) Kb[st][c] = *(const short8*)(kb + c * 512);
    }
    short8 Vb[2][4];
#pragma unroll
    for (int dt = 0; dt < 2; dt++) {
      const ushort* vb = vf + ((size_t)((bh * 2 + dt) * 64 + (k0 >> 4))) * 512 + lane * 8;
#pragma unroll
      for (int c = 0; c < 4; c++) Vb[dt][c] = *(const short8*)(vb + c * 512);
    }
    f32x16 sa[2];
#pragma unroll
    for (int st = 0; st < 2; st++) {
      f32x16 a;
#pragma unroll
      for (int i = 0; i < 16; i++) a[i] = 0.f;
#pragma unroll
      for (int c = 0; c < 4; c++)
        a = __builtin_amdgcn_mfma_f32_32x32x16_bf16(Kb[st][c], Qf[c], a, 0, 0, 0);
      sa[st] = a;
    }
#pragma unroll
    for (int st = 0; st < 2; st++) {
      int kt0 = k0 + st * 32;
      int delta = kt0 - qt * 32;
      if (delta >= 64 || delta <= -64) {
        float bconst = (delta >= 64) ? Tlo : Thi;
#pragma unroll
        for (int rg = 0; rg < 4; rg++) {
          int krun = kt0 + rg * 8 + hh * 4;
          float4 nv = *(const float4*)(negT + b * S_ + krun);
          float p0 = exp2f(fmaf(sa[st][rg * 4 + 0], SCL_, bconst + nv.x));
          float p1 = exp2f(fmaf(sa[st][rg * 4 + 1], SCL_, bconst + nv.y));
          float p2 = exp2f(fmaf(sa[st][rg * 4 + 2], SCL_, bconst + nv.z));
          float p3 = exp2f(fmaf(sa[st][rg * 4 + 3], SCL_, bconst + nv.w));
          l_run += (p0 + p1) + (p2 + p3);
          *(uint2*)&Pt[w][lq][st * 32 + rg * 8 + hh * 4] = make_uint2(pk2(p0, p1), pk2(p2, p3));
        }
      } else {
#pragma unroll
        for (int rg = 0; rg < 4; rg++) {
          int krun = kt0 + rg * 8 + hh * 4;
          float4u bv = *(const float4u*)(Tl + (krun - q + 31 + 1024));
          float4 nv = *(const float4*)(negT + b * S_ + krun);
          float p[4];
#pragma unroll
          for (int i = 0; i < 4; i++) {
            float nvi = (i == 0) ? nv.x : (i == 1) ? nv.y : (i == 2) ? nv.z : nv.w;
            float t0 = (krun + i == q) ? bv[i] : (bv[i] + nvi);
            p[i] = exp2f(fmaf(sa[st][rg * 4 + i], SCL_, t0));
            l_run += p[i];
          }
          *(uint2*)&Pt[w][lq][st * 32 + rg * 8 + hh * 4] = make_uint2(pk2(p[0], p[1]), pk2(p[2], p[3]));
        }
      }
    }
    short8 Pf[4];
#pragma unroll
    for (int c = 0; c < 4; c++) Pf[c] = *(const short8*)&Pt[w][lq][c * 16 + hh * 8];
#pragma unroll
    for (int dt = 0; dt < 2; dt++)
#pragma unroll
      for (int c = 0; c < 4; c++)
        Ot[dt] = __builtin_amdgcn_mfma_f32_32x32x16_bf16(Vb[dt][c], Pf[c], Ot[dt], 0, 0, 0);
  }
  const float* woh = Wol + head * 64 * 4;
  float pe0 = 0.f, pe1 = 0.f, pe2 = 0.f, pe3 = 0.f;
#pragma unroll
  for (int dt = 0; dt < 2; dt++)
#pragma unroll
    for (int rg = 0; rg < 4; rg++)
#pragma unroll
      for (int i = 0; i < 4; i++) {
        int d = dt * 32 + rg * 8 + hh * 4 + i;
        float4 wv = *(const float4*)(woh + d * 4);
        float o = Ot[dt][rg * 4 + i];
        pe0 = fmaf(o, wv.x, pe0);
        pe1 = fmaf(o, wv.y, pe1);
        pe2 = fmaf(o, wv.z, pe2);
        pe3 = fmaf(o, wv.w, pe3);
      }
  pe0 += __shfl_xor(pe0, 32);
  pe1 += __shfl_xor(pe1, 32);
  pe2 += __shfl_xor(pe2, 32);
  pe3 += __shfl_xor(pe3, 32);
  float l_tot = l_run + __shfl_xor(l_run, 32);
  if (hh == 0) {
    float* ao = AOp + (size_t)j * (BS_ * NH_ * 4) + ((size_t)(b * S_ + q) * NH_ + head) * 4;
    *(float4*)ao = make_float4(pe0, pe1, pe2, pe3);
    lpart[((size_t)j * 32 + bh) * S_ + q] = l_tot;
  }
}

__global__ __launch_bounds__(256) void k_resffn(const float* __restrict__ AOp,
                                                const float* __restrict__ lpart,
                                                const float* __restrict__ bo,
                                                const float* __restrict__ g2,
                                                const float* __restrict__ b2n,
                                                const float* __restrict__ Wf1,
                                                const float* __restrict__ bf1,
                                                const float* __restrict__ Wf2,
                                                const float* __restrict__ bf2,
                                                float* __restrict__ x,
                                                const float* __restrict__ Wi,
                                                const float* __restrict__ bi,
                                                const float* __restrict__ g1,
                                                const float* __restrict__ b1n,
                                                ushort* __restrict__ xnbf,
                                                int doinln,
                                                const float* __restrict__ Wout,
                                                const float* __restrict__ bout,
                                                float* __restrict__ out,
                                                int dofinal) {
  int tok = blockIdx.x * 4 + (threadIdx.x >> 6);
  int lane = threadIdx.x & 63;
  int b = tok >> 10, qq = tok & 1023;
  int h = lane & 7;
  int lidx = (b * 8 + h) * 1024 + qq;
  float ls = lpart[lidx] + lpart[lidx + 32768] + lpart[lidx + 65536] + lpart[lidx + 98304];
  float inv = 1.f / ls;
  size_t abase = ((size_t)tok * 8 + h) * 4;
  float4 v0 = *(const float4*)(AOp + abase);
  float4 v1 = *(const float4*)(AOp + abase + 131072);
  float4 v2 = *(const float4*)(AOp + abase + 262144);
  float4 v3 = *(const float4*)(AOp + abase + 393216);
  float r0 = (v0.x + v1.x + v2.x + v3.x) * inv;
  float r1 = (v0.y + v1.y + v2.y + v3.y) * inv;
  float r2 = (v0.z + v1.z + v2.z + v3.z) * inv;
  float r3 = (v0.w + v1.w + v2.w + v3.w) * inv;
#pragma unroll
  for (int o = 1; o < 8; o <<= 1) {
    r0 += __shfl_xor(r0, o); r1 += __shfl_xor(r1, o);
    r2 += __shfl_xor(r2, o); r3 += __shfl_xor(r3, o);
  }
  float4 xo = *(const float4*)&x[tok * 4];
  float x0 = xo.x + r0 + bo[0];
  float x1 = xo.y + r1 + bo[1];
  float x2 = xo.z + r2 + bo[2];
  float x3 = xo.w + r3 + bo[3];
  float mn = 0.25f * (x0 + x1 + x2 + x3);
  float d0 = x0 - mn, d1 = x1 - mn, d2 = x2 - mn, d3 = x3 - mn;
  float var = 0.25f * (d0 * d0 + d1 * d1 + d2 * d2 + d3 * d3);
  float rs = rsqrtf(var + EPS_);
  float l0 = d0 * rs * g2[0] + b2n[0];
  float l1 = d1 * rs * g2[1] + b2n[1];
  float l2 = d2 * rs * g2[2] + b2n[2];
  float l3 = d3 * rs * g2[3] + b2n[3];
  float f0 = 0, f1 = 0, f2 = 0, f3 = 0;
#pragma unroll
  for (int f4 = 0; f4 < FF_ / 64; f4++) {
    int f = lane + f4 * 64;
    float hh = bf1[f] + l0 * Wf1[f] + l1 * Wf1[FF_ + f] + l2 * Wf1[2 * FF_ + f] + l3 * Wf1[3 * FF_ + f];
    hh = fmaxf(hh, 0.f);
    float4 w2 = *(const float4*)&Wf2[f * 4];
    f0 += hh * w2.x; f1 += hh * w2.y; f2 += hh * w2.z; f3 += hh * w2.w;
  }
#pragma unroll
  for (int o = 1; o < 64; o <<= 1) {
    f0 += __shfl_xor(f0, o); f1 += __shfl_xor(f1, o);
    f2 += __shfl_xor(f2, o); f3 += __shfl_xor(f3, o);
  }
  x0 += f0 + bf2[0]; x1 += f1 + bf2[1]; x2 += f2 + bf2[2]; x3 += f3 + bf2[3];
  if (dofinal) {
    if (lane < NT_)
      out[tok * NT_ + lane] = bout[lane] + x0 * Wout[lane] + x1 * Wout[NT_ + lane] +
                              x2 * Wout[2 * NT_ + lane] + x3 * Wout[3 * NT_ + lane];
    return;
  }
  if (lane == 0) *(float4*)&x[tok * 4] = make_float4(x0, x1, x2, x3);
  if (doinln) {
    float xp[8];
    float s = 0.f, qs = 0.f;
#pragma unroll
    for (int k = 0; k < 8; k++) {
      int jj = 64 * k + lane;
      float v = bi[jj] + x0 * Wi[jj] + x1 * Wi[H_ + jj] + x2 * Wi[2 * H_ + jj] + x3 * Wi[3 * H_ + jj];
      xp[k] = v;
      s += v;
      qs += v * v;
    }
#pragma unroll
    for (int o = 1; o < 64; o <<= 1) {
      s += __shfl_xor(s, o);
      qs += __shfl_xor(qs, o);
    }
    float mean = s * (1.f / (float)H_);
    float var1 = qs * (1.f / (float)H_) - mean * mean;
    float rs1 = rsqrtf(var1 + EPS_);
#pragma unroll
    for (int k = 0; k < 8; k++) {
      int jj = 64 * k + lane;
      float v = (xp[k] - mean) * rs1 * g1[jj] + b1n[jj];
      xnbf[tok * H_ + jj] = bf16_rne(v);
    }
  }
}

extern "C" void kernel_launch(void* const* d_in, const int* in_sizes, int n_in,
                              void* d_out, int out_size, void* d_ws, size_t ws_size,
                              hipStream_t stream) {
  const int* patches = (const int*)d_in[0];
  const int* mask = (const int*)d_in[1];
  const float* emb = (const float*)d_in[2];
  const float* Wi = (const float*)d_in[3];
  const float* bi = (const float*)d_in[4];
  const float* Wqkv = (const float*)d_in[5];
  const float* bqkv = (const float*)d_in[6];
  const float* Wo = (const float*)d_in[7];
  const float* bo = (const float*)d_in[8];
  const float* g1 = (const float*)d_in[9];
  const float* b1n = (const float*)d_in[10];
  const float* Wf1 = (const float*)d_in[11];
  const float* bf1 = (const float*)d_in[12];
  const float* Wf2 = (const float*)d_in[13];
  const float* bf2 = (const float*)d_in[14];
  const float* g2 = (const float*)d_in[15];
  const float* b2n = (const float*)d_in[16];
  const float* relemb = (const float*)d_in[17];
  const float* Wout = (const float*)d_in[18];
  const float* bout = (const float*)d_in[19];
  float* out = (float*)d_out;

  char* p = (char*)d_ws;
  float* x = (float*)p;          p += (size_t)BS_ * 4 * 4;
  float* T = (float*)p;          p += (size_t)L_ * 2112 * 4;
  float* negT = (float*)p;       p += (size_t)BS_ * 4;
  float* AOp = (float*)p;        p += (size_t)KSPLIT_ * BS_ * NH_ * 4 * 4;
  float* lpart = (float*)p;      p += (size_t)KSPLIT_ * 32 * 1024 * 4;
  ushort* xnbf = (ushort*)p;     p += (size_t)BS_ * H_ * 2;
  ushort* Wt = (ushort*)p;       p += (size_t)L_ * 1536 * 512 * 2;
  ushort* qf = (ushort*)p;       p += (size_t)32 * 1024 * 64 * 2;
  ushort* kf = (ushort*)p;       p += (size_t)32 * 1024 * 64 * 2;
  ushort* vf = (ushort*)p;       p += (size_t)32 * 64 * 1024 * 2;

  static int coop = -1;
  if (coop < 0) {
    int dev = 0;
    (void)hipGetDevice(&dev);
    int attr = 0;
    if (hipDeviceGetAttribute(&attr, hipDeviceAttributeCooperativeLaunch, dev) != hipSuccess) attr = 0;
    int ncu = 0;
    if (hipDeviceGetAttribute(&ncu, hipDeviceAttributeMultiprocessorCount, dev) != hipSuccess) ncu = 0;
    int nb = 0;
    if (hipOccupancyMaxActiveBlocksPerMultiprocessor(&nb, k_fused, 256, 0) != hipSuccess) nb = 0;
    coop = (attr && (size_t)nb * (size_t)ncu >= 512) ? 1 : 0;
  }

  if (coop) {
    FP fp;
    fp.patches = patches; fp.mask = mask; fp.emb = emb; fp.relemb = relemb;
    fp.Wqkv = Wqkv; fp.Wi = Wi; fp.bi = bi; fp.g1 = g1; fp.b1n = b1n;
    fp.bqkv = bqkv; fp.Wo = Wo; fp.bo = bo; fp.g2 = g2; fp.b2n = b2n;
    fp.Wf1 = Wf1; fp.bf1 = bf1; fp.Wf2 = Wf2; fp.bf2 = bf2;
    fp.Wout = Wout; fp.bout = bout;
    fp.x = x; fp.T = T; fp.negT = negT; fp.AOp = AOp; fp.lpart = lpart; fp.out = out;
    fp.xnbf = xnbf; fp.Wt = Wt; fp.qf = qf; fp.kf = kf; fp.vf = vf;
    void* args[] = {(void*)&fp};
    hipError_t e = hipLaunchCooperativeKernel((const void*)k_fused, dim3(512), dim3(256),
                                              args, 0, stream);
    if (e == hipSuccess) return;
    coop = 0;  // fall through to the proven multi-launch path
  }

  k_pre<<<dim3(1841), dim3(256), 0, stream>>>(patches, mask, emb, relemb, Wqkv,
                                              Wi, bi, g1, b1n, x, T, negT, Wt, xnbf);
  for (int l = 0; l < L_; l++) {
    k_qkv<<<dim3(12, 32), dim3(256), 0, stream>>>(xnbf, Wt + (size_t)l * 1536 * 512,
                                                  bqkv + l * 3 * H_, qf, kf, vf);
    k_attn<<<dim3(1024), dim3(256), 0, stream>>>(qf, kf, vf, T + l * 2112, negT,
                                                 Wo + l * H_ * E_, AOp, lpart);
    int nl = l + 1;
    k_resffn<<<dim3(1024), dim3(256), 0, stream>>>(
        AOp, lpart, bo + l * E_, g2 + l * E_, b2n + l * E_,
        Wf1 + l * E_ * FF_, bf1 + l * FF_, Wf2 + l * FF_ * E_, bf2 + l * E_, x,
        Wi + nl * E_ * H_, bi + nl * H_, g1 + nl * H_, b1n + nl * H_, xnbf,
        (l < L_ - 1) ? 1 : 0, Wout, bout, out, (l == L_ - 1) ? 1 : 0);
  }
}

// Round 2
// 331.930 us; speedup vs baseline: 1.0028x; 1.0028x over previous
//
#include <hip/hip_runtime.h>
#include <hip/hip_bf16.h>
#include <math.h>

#define B_ 4
#define S_ 1024
#define H_ 512
#define NH_ 8
#define HD_ 64
#define FF_ 1024
#define E_ 4
#define L_ 4
#define NT_ 17
#define BS_ 4096
#define EPS_ 1e-5f
#define L2E_ 1.4426950408889634f
#define SCL_ 0.18033688011112042f   // 0.125 * log2(e)
#define KSPLIT_ 4
#define GRID_F 512

typedef __attribute__((ext_vector_type(8))) short short8;
typedef __attribute__((ext_vector_type(16))) float f32x16;
typedef float float4u __attribute__((ext_vector_type(4), aligned(4)));

__device__ inline ushort bf16_rne(float f) {
  unsigned u = __builtin_bit_cast(unsigned, f);
  u += 0x7FFFu + ((u >> 16) & 1u);
  return (ushort)(u >> 16);
}
__device__ inline unsigned pk_bf16(float a, float b) {
  return (unsigned)bf16_rne(a) | ((unsigned)bf16_rne(b) << 16);
}
// fast pack: round-half-away + v_perm_b32 (3 VALU ops)
__device__ inline unsigned pk2(float a, float b) {
  unsigned ua = __builtin_bit_cast(unsigned, a) + 0x8000u;
  unsigned ub = __builtin_bit_cast(unsigned, b) + 0x8000u;
  return __builtin_amdgcn_perm(ub, ua, 0x07060302u);
}
__device__ inline float ubf2f(ushort u) {
  return __builtin_bit_cast(float, ((unsigned)u) << 16);
}

// ===========================================================================
// R19: persistent fused kernel with SOFTWARE grid barrier.
// R18 post-mortem: dur identical to baseline (332.9 vs 332.3) + rocprof
// blowup => hipLaunchCooperativeKernel failed under graph capture; fallback
// path was what got timed. Fused structure never measured.
// Fix: normal <<<512,256>>> launch (capture-safe) + device-scope atomic
// ticket barrier (monotonic counter, no reset race), __threadfence() both
// sides for cross-XCD visibility (G16), hipMemsetAsync zeroes the counter
// each invocation (memsets are capture-safe; harness reset() uses them).
// Co-residency: __launch_bounds__(256,2) + 73.7KiB LDS => exactly 2
// blocks/CU x 256 CU = 512; runtime occupancy gate + bounded-spin safety
// valve (wrong answer, not hang, if assumption ever breaks).
// ===========================================================================

struct FP {
  const int* patches; const int* mask;
  const float* emb; const float* relemb; const float* Wqkv;
  const float* Wi; const float* bi; const float* g1; const float* b1n;
  const float* bqkv; const float* Wo; const float* bo;
  const float* g2; const float* b2n;
  const float* Wf1; const float* bf1; const float* Wf2; const float* bf2;
  const float* Wout; const float* bout;
  float* x; float* T; float* negT; float* AOp; float* lpart; float* out;
  ushort* xnbf; ushort* Wt; ushort* qf; ushort* kf; ushort* vf;
  unsigned* bar;
};

__device__ inline void gsync(unsigned* bar) {
  __syncthreads();  // all waves of block: vmcnt(0) drained before barrier
  if (threadIdx.x == 0) {
    __threadfence();  // release: prior global writes visible device-wide
    unsigned a = __hip_atomic_fetch_add(bar, 1u, __ATOMIC_ACQ_REL,
                                        __HIP_MEMORY_SCOPE_AGENT);
    unsigned target = (a / GRID_F + 1u) * GRID_F;
    unsigned spins = 0;
    while (__hip_atomic_load(bar, __ATOMIC_ACQUIRE,
                             __HIP_MEMORY_SCOPE_AGENT) < target) {
      __builtin_amdgcn_s_sleep(8);
      if (++spins > 1000000u) break;  // safety valve: fail wrong, not hung
    }
    __threadfence();  // acquire: invalidate stale cached lines
  }
  __syncthreads();
}

__global__ __launch_bounds__(256, 2) void k_fused(FP p) {
  __shared__ union {
    struct { ushort At[2][128][72]; ushort Bt[2][128][72]; } g;  // qkv: 73728 B
    struct { ushort Tr[64][72]; } pr;                            // pre transpose
    struct { ushort Pt[4][32][72]; } a;                          // attn P tiles
  } sm;
  const int bid = blockIdx.x;
  const int t = threadIdx.x;
  unsigned* bar = p.bar;

  // local __restrict__ views (FP members alias-opaque otherwise)
  const int* __restrict__ patches = p.patches;
  const int* __restrict__ mask = p.mask;
  const float* __restrict__ emb = p.emb;
  const float* __restrict__ relemb = p.relemb;
  const float* __restrict__ Wqkv = p.Wqkv;
  const float* __restrict__ WiB = p.Wi;
  const float* __restrict__ biB = p.bi;
  const float* __restrict__ g1B = p.g1;
  const float* __restrict__ b1nB = p.b1n;
  const float* __restrict__ bqkvB = p.bqkv;
  const float* __restrict__ WoB = p.Wo;
  const float* __restrict__ boB = p.bo;
  const float* __restrict__ g2B = p.g2;
  const float* __restrict__ b2nB = p.b2n;
  const float* __restrict__ Wf1B = p.Wf1;
  const float* __restrict__ bf1B = p.bf1;
  const float* __restrict__ Wf2B = p.Wf2;
  const float* __restrict__ bf2B = p.bf2;
  const float* __restrict__ Wout = p.Wout;
  const float* __restrict__ bout = p.bout;
  float* __restrict__ x = p.x;
  float* __restrict__ T = p.T;
  float* __restrict__ negT = p.negT;
  float* __restrict__ AOp = p.AOp;
  float* __restrict__ lpart = p.lpart;
  float* __restrict__ out = p.out;
  ushort* __restrict__ xnbf = p.xnbf;
  ushort* __restrict__ Wt = p.Wt;
  ushort* __restrict__ qf = p.qf;
  ushort* __restrict__ kf = p.kf;
  ushort* __restrict__ vf = p.vf;

  // ================= phase 0: prologue (was k_pre, 1841 virtual blocks) ====
#pragma unroll 1
  for (int vb = bid; vb < 1841; vb += GRID_F) {
    if (vb < 768) {
      ushort(&Tr)[64][72] = sm.pr.Tr;
      int l = vb / 192, rem = vb % 192;
      int k0 = (rem / 24) * 64, n0 = (rem % 24) * 64;
      const float* src = Wqkv + (size_t)l * 512 * 1536;
      int row = t >> 4, c4 = (t & 15) * 4;
#pragma unroll
      for (int rr = 0; rr < 4; rr++) {
        int k = rr * 16 + row;
        float4 v = *(const float4*)(src + (size_t)(k0 + k) * 1536 + n0 + c4);
        Tr[c4 + 0][k] = bf16_rne(v.x);
        Tr[c4 + 1][k] = bf16_rne(v.y);
        Tr[c4 + 2][k] = bf16_rne(v.z);
        Tr[c4 + 3][k] = bf16_rne(v.w);
      }
      __syncthreads();
      int nrow = t >> 2, kc = (t & 3) * 16;
      ushort* dst = Wt + ((size_t)(l * 1536 + n0 + nrow)) * 512 + k0 + kc;
      *(uint4*)dst = *(uint4*)&Tr[nrow][kc];
      *(uint4*)(dst + 8) = *(uint4*)&Tr[nrow][kc + 8];
      __syncthreads();  // Tr reused by next vb iteration of this block
    } else if (vb < 817) {
      int gid = (vb - 768) * 256 + t;
      if (gid < BS_) {
        int mk = mask[gid];
        int row = mk ? (NT_ - 1) : patches[gid];
        ((float4*)x)[gid] = ((const float4*)emb)[row];
        negT[gid] = mk ? -1e30f : 0.f;
      } else {
        int idx = gid - BS_;
        if (idx < L_ * 2112) {
          int l = idx / 2112, j = idx - l * 2112;
          int c = 1086 - j;
          c = c < 0 ? 0 : (c > 62 ? 62 : c);
          const float* src = relemb + (size_t)(l * 63 + c) * 64;
          float s = 0.f;
#pragma unroll
          for (int d = 0; d < 64; d++) s += src[d];
          T[idx] = s * L2E_;
        }
      }
    } else {
      int token = (vb - 817) * 4 + (t >> 6);
      int lane = t & 63;
      int mk = mask[token];
      int row = mk ? (NT_ - 1) : patches[token];
      float4 e = ((const float4*)emb)[row];
      float xp[8];
      float s = 0.f, qs = 0.f;
#pragma unroll
      for (int k = 0; k < 8; k++) {
        int jj = 64 * k + lane;
        float v = biB[jj] + e.x * WiB[jj] + e.y * WiB[H_ + jj] + e.z * WiB[2 * H_ + jj] + e.w * WiB[3 * H_ + jj];
        xp[k] = v; s += v; qs += v * v;
      }
#pragma unroll
      for (int o = 1; o < 64; o <<= 1) { s += __shfl_xor(s, o); qs += __shfl_xor(qs, o); }
      float mean = s * (1.f / (float)H_);
      float var = qs * (1.f / (float)H_) - mean * mean;
      float rs = rsqrtf(var + EPS_);
#pragma unroll
      for (int k = 0; k < 8; k++) {
        int jj = 64 * k + lane;
        xnbf[token * H_ + jj] = bf16_rne((xp[k] - mean) * rs * g1B[jj] + b1nB[jj]);
      }
    }
  }
  gsync(bar);

#pragma unroll 1
  for (int l = 0; l < L_; l++) {
    // ---------------- qkv (blocks 0..383) ----------------
    if (bid < 384) {
      ushort(&At)[2][128][72] = sm.g.At;
      ushort(&Bt)[2][128][72] = sm.g.Bt;
      const ushort* Aq = xnbf;
      const ushort* Wtl = Wt + (size_t)l * 1536 * 512;
      const float* biasq = bqkvB + l * 3 * H_;
      int n0 = (bid % 12) * 128, m0 = (bid / 12) * 128;
      bool trq = (n0 < 1024);
      int w = t >> 6, lq = t & 31, hh = (t >> 5) & 1;
      int wm = (w & 1) * 64, wn = (w >> 1) * 64;
      f32x16 acc[2][2];
#pragma unroll
      for (int mt = 0; mt < 2; mt++)
#pragma unroll
        for (int nt = 0; nt < 2; nt++)
#pragma unroll
          for (int i = 0; i < 16; i++) acc[mt][nt][i] = 0.f;
      uint4 ar[4], br[4];

#define FQLOADREGS(k0_)                                                         \
  {                                                                             \
    _Pragma("unroll") for (int jx = 0; jx < 4; jx++) {                          \
      int idl = 256 * jx + t;                                                   \
      int row = idl >> 3, u = idl & 7;                                          \
      ar[jx] = *(const uint4*)(Aq + (size_t)(m0 + row) * 512 + (k0_) + u * 8);  \
      br[jx] = *(const uint4*)(Wtl + (size_t)(n0 + row) * 512 + (k0_) + u * 8); \
    }                                                                           \
  }
#define FQWRITELDS(buf_)                                                        \
  {                                                                             \
    _Pragma("unroll") for (int jx = 0; jx < 4; jx++) {                          \
      int idl = 256 * jx + t;                                                   \
      int row = idl >> 3, u = idl & 7;                                          \
      *(uint4*)&At[buf_][row][u * 8] = ar[jx];                                  \
      *(uint4*)&Bt[buf_][row][u * 8] = br[jx];                                  \
    }                                                                           \
  }
      FQLOADREGS(0);
      FQWRITELDS(0);
      __syncthreads();
      for (int it = 0; it < 8; it++) {
        int buf = it & 1;
        if (it < 7) { FQLOADREGS((it + 1) * 64); }
#pragma unroll
        for (int kc = 0; kc < 4; kc++) {
          short8 af[2], bfr[2];
#pragma unroll
          for (int mt = 0; mt < 2; mt++) af[mt] = *(const short8*)&At[buf][wm + mt * 32 + lq][kc * 16 + hh * 8];
#pragma unroll
          for (int nt = 0; nt < 2; nt++) bfr[nt] = *(const short8*)&Bt[buf][wn + nt * 32 + lq][kc * 16 + hh * 8];
#pragma unroll
          for (int mt = 0; mt < 2; mt++)
#pragma unroll
            for (int nt = 0; nt < 2; nt++) {
              if (trq)
                acc[mt][nt] = __builtin_amdgcn_mfma_f32_32x32x16_bf16(bfr[nt], af[mt], acc[mt][nt], 0, 0, 0);
              else
                acc[mt][nt] = __builtin_amdgcn_mfma_f32_32x32x16_bf16(af[mt], bfr[nt], acc[mt][nt], 0, 0, 0);
            }
        }
        if (it < 7) {
          FQWRITELDS(buf ^ 1);
          __syncthreads();
        }
      }
#undef FQLOADREGS
#undef FQWRITELDS

      if (trq) {
#pragma unroll
        for (int mt = 0; mt < 2; mt++) {
          int token = m0 + wm + mt * 32 + lq;
          int bb = token >> 10, sr = token & 1023;
          int qt = sr >> 5, lqp = sr & 31;
#pragma unroll
          for (int nt = 0; nt < 2; nt++) {
            int nn = n0 + wn + nt * 32;
            int nloc = (nn < 512) ? nn : nn - 512;
            ushort* dst = (nn < 512) ? qf : kf;
            int hd = nloc >> 6;
            int bh = bb * 8 + hd;
            size_t fragbase = ((size_t)(bh * 32 + qt)) * 4 * 512;
#pragma unroll
            for (int rg = 0; rg < 4; rg++) {
              int nbase = nn + rg * 8 + hh * 4;
              float4 bv = *(const float4*)(biasq + nbase);
              float v0 = acc[mt][nt][rg * 4 + 0] + bv.x;
              float v1 = acc[mt][nt][rg * 4 + 1] + bv.y;
              float v2 = acc[mt][nt][rg * 4 + 2] + bv.z;
              float v3 = acc[mt][nt][rg * 4 + 3] + bv.w;
              int d0 = (nloc & 63) + rg * 8 + hh * 4;
              size_t addr = fragbase + (size_t)(d0 >> 4) * 512 +
                            (size_t)(((d0 >> 3) & 1) * 32 + lqp) * 8 + (d0 & 7);
              *(uint2*)(dst + addr) = make_uint2(pk_bf16(v0, v1), pk_bf16(v2, v3));
            }
          }
        }
      } else {
#pragma unroll
        for (int nt = 0; nt < 2; nt++) {
          int n = n0 + wn + nt * 32 + lq;
          int nloc = n - 1024;
          int hd = nloc >> 6, d = nloc & 63;
          float bb_ = biasq[n];
#pragma unroll
          for (int mt = 0; mt < 2; mt++) {
#pragma unroll
            for (int rg = 0; rg < 4; rg++) {
              int tb = m0 + wm + mt * 32 + rg * 8 + hh * 4;
              int bb = tb >> 10, sr = tb & 1023;
              int bh = bb * 8 + hd;
              float v0 = acc[mt][nt][rg * 4 + 0] + bb_;
              float v1 = acc[mt][nt][rg * 4 + 1] + bb_;
              float v2 = acc[mt][nt][rg * 4 + 2] + bb_;
              float v3 = acc[mt][nt][rg * 4 + 3] + bb_;
              size_t addr = ((size_t)((bh * 2 + (d >> 5)) * 64 + (sr >> 4))) * 512 +
                            (size_t)(((sr >> 3) & 1) * 32 + (d & 31)) * 8 + (sr & 7);
              *(uint2*)(vf + addr) = make_uint2(pk_bf16(v0, v1), pk_bf16(v2, v3));
            }
          }
        }
      }
    }
    gsync(bar);

    // ---------------- attn: slots bid and bid+512 (same bh/qt => Qf reuse) --
    {
      const float* Tl = T + l * 2112;
      const float* Wol = WoB + (size_t)l * H_ * E_;
      ushort(&Pt)[4][32][72] = sm.a.Pt;
      int w = t >> 6, lane = t & 63;
      int lq = lane & 31, hh = lane >> 5;
      int bh = bid & 31;
      int slot = bid >> 5;           // [0,16)
      int qtg = slot & 7, j0 = slot >> 3;   // j0 in {0,1}; second pass j0+2
      int b = bh >> 3, head = bh & 7;
      int qt = qtg * 4 + w;
      int q = qt * 32 + lq;

      const ushort* qbase = qf + ((size_t)(bh * 32 + qt)) * 2048 + lane * 8;
      short8 Qf[4];
#pragma unroll
      for (int c = 0; c < 4; c++) Qf[c] = *(const short8*)(qbase + c * 512);

      float Tlo = Tl[1086];
      float Thi = Tl[1024];

#pragma unroll 1
      for (int jj = 0; jj < 2; jj++) {
        int j = j0 + 2 * jj;
        int kstart = j * 256;
        float l_run = 0.f;
        f32x16 Ot[2];
#pragma unroll
        for (int dt = 0; dt < 2; dt++)
#pragma unroll
          for (int i = 0; i < 16; i++) Ot[dt][i] = 0.f;

        for (int it = 0; it < 4; it++) {
          int k0 = kstart + it * 64;
          short8 Kb[2][4];
#pragma unroll
          for (int st = 0; st < 2; st++) {
            const ushort* kb = kf + ((size_t)(bh * 32 + (k0 >> 5) + st)) * 2048 + lane * 8;
#pragma unroll
            for (int c = 0; c < 4; c++) Kb[st][c] = *(const short8*)(kb + c * 512);
          }
          short8 Vb[2][4];
#pragma unroll
          for (int dt = 0; dt < 2; dt++) {
            const ushort* vbp = vf + ((size_t)((bh * 2 + dt) * 64 + (k0 >> 4))) * 512 + lane * 8;
#pragma unroll
            for (int c = 0; c < 4; c++) Vb[dt][c] = *(const short8*)(vbp + c * 512);
          }
          // ---- S^T ----
          f32x16 sa[2];
#pragma unroll
          for (int st = 0; st < 2; st++) {
            f32x16 a;
#pragma unroll
            for (int i = 0; i < 16; i++) a[i] = 0.f;
#pragma unroll
            for (int c = 0; c < 4; c++)
              a = __builtin_amdgcn_mfma_f32_32x32x16_bf16(Kb[st][c], Qf[c], a, 0, 0, 0);
            sa[st] = a;
          }
          // ---- softmax: band-specialized ----
#pragma unroll
          for (int st = 0; st < 2; st++) {
            int kt0 = k0 + st * 32;
            int delta = kt0 - qt * 32;
            if (delta >= 64 || delta <= -64) {
              float bconst = (delta >= 64) ? Tlo : Thi;
#pragma unroll
              for (int rg = 0; rg < 4; rg++) {
                int krun = kt0 + rg * 8 + hh * 4;
                float4 nv = *(const float4*)(negT + b * S_ + krun);
                float p0 = exp2f(fmaf(sa[st][rg * 4 + 0], SCL_, bconst + nv.x));
                float p1 = exp2f(fmaf(sa[st][rg * 4 + 1], SCL_, bconst + nv.y));
                float p2 = exp2f(fmaf(sa[st][rg * 4 + 2], SCL_, bconst + nv.z));
                float p3 = exp2f(fmaf(sa[st][rg * 4 + 3], SCL_, bconst + nv.w));
                l_run += (p0 + p1) + (p2 + p3);
                *(uint2*)&Pt[w][lq][st * 32 + rg * 8 + hh * 4] = make_uint2(pk2(p0, p1), pk2(p2, p3));
              }
            } else {
#pragma unroll
              for (int rg = 0; rg < 4; rg++) {
                int krun = kt0 + rg * 8 + hh * 4;
                float4u bv = *(const float4u*)(Tl + (krun - q + 31 + 1024));
                float4 nv = *(const float4*)(negT + b * S_ + krun);
                float pp[4];
#pragma unroll
                for (int i = 0; i < 4; i++) {
                  float nvi = (i == 0) ? nv.x : (i == 1) ? nv.y : (i == 2) ? nv.z : nv.w;
                  float t0 = (krun + i == q) ? bv[i] : (bv[i] + nvi);
                  pp[i] = exp2f(fmaf(sa[st][rg * 4 + i], SCL_, t0));
                  l_run += pp[i];
                }
                *(uint2*)&Pt[w][lq][st * 32 + rg * 8 + hh * 4] = make_uint2(pk2(pp[0], pp[1]), pk2(pp[2], pp[3]));
              }
            }
          }
          // ---- O^T += V^T . P ----
          short8 Pf[4];
#pragma unroll
          for (int c = 0; c < 4; c++) Pf[c] = *(const short8*)&Pt[w][lq][c * 16 + hh * 8];
#pragma unroll
          for (int dt = 0; dt < 2; dt++)
#pragma unroll
            for (int c = 0; c < 4; c++)
              Ot[dt] = __builtin_amdgcn_mfma_f32_32x32x16_bf16(Vb[dt][c], Pf[c], Ot[dt], 0, 0, 0);
        }
        // ---- epilogue: project through Wo[head], store private j-slot partial
        const float* woh = Wol + head * 64 * 4;
        float pe0 = 0.f, pe1 = 0.f, pe2 = 0.f, pe3 = 0.f;
#pragma unroll
        for (int dt = 0; dt < 2; dt++)
#pragma unroll
          for (int rg = 0; rg < 4; rg++)
#pragma unroll
            for (int i = 0; i < 4; i++) {
              int d = dt * 32 + rg * 8 + hh * 4 + i;
              float4 wv = *(const float4*)(woh + d * 4);
              float o = Ot[dt][rg * 4 + i];
              pe0 = fmaf(o, wv.x, pe0);
              pe1 = fmaf(o, wv.y, pe1);
              pe2 = fmaf(o, wv.z, pe2);
              pe3 = fmaf(o, wv.w, pe3);
            }
        pe0 += __shfl_xor(pe0, 32);
        pe1 += __shfl_xor(pe1, 32);
        pe2 += __shfl_xor(pe2, 32);
        pe3 += __shfl_xor(pe3, 32);
        float l_tot = l_run + __shfl_xor(l_run, 32);
        if (hh == 0) {
          float* ao = AOp + (size_t)j * (BS_ * NH_ * 4) + ((size_t)(b * S_ + q) * NH_ + head) * 4;
          *(float4*)ao = make_float4(pe0, pe1, pe2, pe3);
          lpart[((size_t)j * 32 + bh) * S_ + q] = l_tot;
        }
      }
    }
    gsync(bar);

    // ---------------- resffn: 2 token-groups per block ----------------
    {
      const float* bo_l = boB + l * E_;
      const float* g2_l = g2B + l * E_;
      const float* b2n_l = b2nB + l * E_;
      const float* Wf1_l = Wf1B + (size_t)l * E_ * FF_;
      const float* bf1_l = bf1B + (size_t)l * FF_;
      const float* Wf2_l = Wf2B + (size_t)l * FF_ * E_;
      const float* bf2_l = bf2B + l * E_;
      const float* Wi_n = WiB + (size_t)(l + 1) * E_ * H_;
      const float* bi_n = biB + (size_t)(l + 1) * H_;
      const float* g1_n = g1B + (size_t)(l + 1) * H_;
      const float* b1n_n = b1nB + (size_t)(l + 1) * H_;
      int lane = t & 63;
      int h = lane & 7;
#pragma unroll 1
      for (int gg = 0; gg < 2; gg++) {
        int tok = (bid * 2 + gg) * 4 + (t >> 6);
        int bq = tok >> 10, qq = tok & 1023;
        int lidx = (bq * 8 + h) * 1024 + qq;
        float ls = lpart[lidx] + lpart[lidx + 32768] + lpart[lidx + 65536] + lpart[lidx + 98304];
        float inv = 1.f / ls;
        size_t abase = ((size_t)tok * 8 + h) * 4;
        float4 v0 = *(const float4*)(AOp + abase);
        float4 v1 = *(const float4*)(AOp + abase + 131072);
        float4 v2 = *(const float4*)(AOp + abase + 262144);
        float4 v3 = *(const float4*)(AOp + abase + 393216);
        float r0 = (v0.x + v1.x + v2.x + v3.x) * inv;
        float r1 = (v0.y + v1.y + v2.y + v3.y) * inv;
        float r2 = (v0.z + v1.z + v2.z + v3.z) * inv;
        float r3 = (v0.w + v1.w + v2.w + v3.w) * inv;
#pragma unroll
        for (int o = 1; o < 8; o <<= 1) {
          r0 += __shfl_xor(r0, o); r1 += __shfl_xor(r1, o);
          r2 += __shfl_xor(r2, o); r3 += __shfl_xor(r3, o);
        }
        float4 xo = *(const float4*)&x[tok * 4];
        float x0 = xo.x + r0 + bo_l[0];
        float x1 = xo.y + r1 + bo_l[1];
        float x2 = xo.z + r2 + bo_l[2];
        float x3 = xo.w + r3 + bo_l[3];
        float mn = 0.25f * (x0 + x1 + x2 + x3);
        float d0 = x0 - mn, d1 = x1 - mn, d2 = x2 - mn, d3 = x3 - mn;
        float var = 0.25f * (d0 * d0 + d1 * d1 + d2 * d2 + d3 * d3);
        float rs = rsqrtf(var + EPS_);
        float l0 = d0 * rs * g2_l[0] + b2n_l[0];
        float l1 = d1 * rs * g2_l[1] + b2n_l[1];
        float l2 = d2 * rs * g2_l[2] + b2n_l[2];
        float l3 = d3 * rs * g2_l[3] + b2n_l[3];
        float f0 = 0, f1 = 0, f2 = 0, f3 = 0;
#pragma unroll
        for (int f4 = 0; f4 < FF_ / 64; f4++) {
          int f = lane + f4 * 64;
          float hv = bf1_l[f] + l0 * Wf1_l[f] + l1 * Wf1_l[FF_ + f] + l2 * Wf1_l[2 * FF_ + f] + l3 * Wf1_l[3 * FF_ + f];
          hv = fmaxf(hv, 0.f);
          float4 w2 = *(const float4*)&Wf2_l[f * 4];
          f0 += hv * w2.x; f1 += hv * w2.y; f2 += hv * w2.z; f3 += hv * w2.w;
        }
#pragma unroll
        for (int o = 1; o < 64; o <<= 1) {
          f0 += __shfl_xor(f0, o); f1 += __shfl_xor(f1, o);
          f2 += __shfl_xor(f2, o); f3 += __shfl_xor(f3, o);
        }
        x0 += f0 + bf2_l[0]; x1 += f1 + bf2_l[1]; x2 += f2 + bf2_l[2]; x3 += f3 + bf2_l[3];
        if (l == L_ - 1) {
          if (lane < NT_)
            out[tok * NT_ + lane] = bout[lane] + x0 * Wout[lane] + x1 * Wout[NT_ + lane] +
                                    x2 * Wout[2 * NT_ + lane] + x3 * Wout[3 * NT_ + lane];
        } else {
          if (lane == 0) *(float4*)&x[tok * 4] = make_float4(x0, x1, x2, x3);
          float xp[8];
          float s = 0.f, qs = 0.f;
#pragma unroll
          for (int k = 0; k < 8; k++) {
            int jj = 64 * k + lane;
            float v = bi_n[jj] + x0 * Wi_n[jj] + x1 * Wi_n[H_ + jj] + x2 * Wi_n[2 * H_ + jj] + x3 * Wi_n[3 * H_ + jj];
            xp[k] = v;
            s += v;
            qs += v * v;
          }
#pragma unroll
          for (int o = 1; o < 64; o <<= 1) {
            s += __shfl_xor(s, o);
            qs += __shfl_xor(qs, o);
          }
          float mean = s * (1.f / (float)H_);
          float var1 = qs * (1.f / (float)H_) - mean * mean;
          float rs1 = rsqrtf(var1 + EPS_);
#pragma unroll
          for (int k = 0; k < 8; k++) {
            int jj = 64 * k + lane;
            float v = (xp[k] - mean) * rs1 * g1_n[jj] + b1n_n[jj];
            xnbf[tok * H_ + jj] = bf16_rne(v);
          }
        }
      }
    }
    if (l < L_ - 1) gsync(bar);
  }
}

// ===========================================================================
// Fallback path: original 13-launch pipeline (verified at 331us) -- used only
// if the occupancy gate says 512 blocks cannot be co-resident.
// ===========================================================================

__global__ __launch_bounds__(256) void k_pre(const int* __restrict__ patches,
                                             const int* __restrict__ mask,
                                             const float* __restrict__ emb,
                                             const float* __restrict__ relemb,
                                             const float* __restrict__ W,
                                             const float* __restrict__ Wi,
                                             const float* __restrict__ bi,
                                             const float* __restrict__ g1,
                                             const float* __restrict__ b1n,
                                             float* __restrict__ x,
                                             float* __restrict__ T,
                                             float* __restrict__ negT,
                                             ushort* __restrict__ Wt,
                                             ushort* __restrict__ xnbf) {
  __shared__ ushort Tr[64][72];
  int bid = blockIdx.x, t = threadIdx.x;
  if (bid < 768) {
    int l = bid / 192, rem = bid % 192;
    int k0 = (rem / 24) * 64, n0 = (rem % 24) * 64;
    const float* src = W + (size_t)l * 512 * 1536;
    int row = t >> 4, c4 = (t & 15) * 4;
#pragma unroll
    for (int rr = 0; rr < 4; rr++) {
      int k = rr * 16 + row;
      float4 v = *(const float4*)(src + (size_t)(k0 + k) * 1536 + n0 + c4);
      Tr[c4 + 0][k] = bf16_rne(v.x);
      Tr[c4 + 1][k] = bf16_rne(v.y);
      Tr[c4 + 2][k] = bf16_rne(v.z);
      Tr[c4 + 3][k] = bf16_rne(v.w);
    }
    __syncthreads();
    int nrow = t >> 2, kc = (t & 3) * 16;
    ushort* dst = Wt + ((size_t)(l * 1536 + n0 + nrow)) * 512 + k0 + kc;
    *(uint4*)dst = *(uint4*)&Tr[nrow][kc];
    *(uint4*)(dst + 8) = *(uint4*)&Tr[nrow][kc + 8];
  } else if (bid < 817) {
    int gid = (bid - 768) * 256 + t;
    if (gid < BS_) {
      int mk = mask[gid];
      int row = mk ? (NT_ - 1) : patches[gid];
      ((float4*)x)[gid] = ((const float4*)emb)[row];
      negT[gid] = mk ? -1e30f : 0.f;
    } else {
      int idx = gid - BS_;
      if (idx < L_ * 2112) {
        int l = idx / 2112, j = idx - l * 2112;
        int c = 1086 - j;
        c = c < 0 ? 0 : (c > 62 ? 62 : c);
        const float* src = relemb + (size_t)(l * 63 + c) * 64;
        float s = 0.f;
#pragma unroll
        for (int d = 0; d < 64; d++) s += src[d];
        T[idx] = s * L2E_;
      }
    }
  } else {
    int token = (bid - 817) * 4 + (t >> 6);
    int lane = t & 63;
    int mk = mask[token];
    int row = mk ? (NT_ - 1) : patches[token];
    float4 e = ((const float4*)emb)[row];
    float xp[8];
    float s = 0.f, qs = 0.f;
#pragma unroll
    for (int k = 0; k < 8; k++) {
      int jj = 64 * k + lane;
      float v = bi[jj] + e.x * Wi[jj] + e.y * Wi[H_ + jj] + e.z * Wi[2 * H_ + jj] + e.w * Wi[3 * H_ + jj];
      xp[k] = v; s += v; qs += v * v;
    }
#pragma unroll
    for (int o = 1; o < 64; o <<= 1) { s += __shfl_xor(s, o); qs += __shfl_xor(qs, o); }
    float mean = s * (1.f / (float)H_);
    float var = qs * (1.f / (float)H_) - mean * mean;
    float rs = rsqrtf(var + EPS_);
#pragma unroll
    for (int k = 0; k < 8; k++) {
      int jj = 64 * k + lane;
      xnbf[token * H_ + jj] = bf16_rne((xp[k] - mean) * rs * g1[jj] + b1n[jj]);
    }
  }
}

__global__ __launch_bounds__(256, 2) void k_qkv(const ushort* __restrict__ A,
                                                const ushort* __restrict__ Wt,
                                                const float* __restrict__ bias,
                                                ushort* __restrict__ qf,
                                                ushort* __restrict__ kf,
                                                ushort* __restrict__ vf) {
  __shared__ ushort At[2][128][72];
  __shared__ ushort Bt[2][128][72];
  int t = threadIdx.x;
  int n0 = blockIdx.x * 128, m0 = blockIdx.y * 128;
  bool tr = (n0 < 1024);
  int w = t >> 6, lq = t & 31, hh = (t >> 5) & 1;
  int wm = (w & 1) * 64, wn = (w >> 1) * 64;
  f32x16 acc[2][2];
#pragma unroll
  for (int mt = 0; mt < 2; mt++)
#pragma unroll
    for (int nt = 0; nt < 2; nt++)
#pragma unroll
      for (int i = 0; i < 16; i++) acc[mt][nt][i] = 0.f;

  uint4 ar[4], br[4];

#define QLOADREGS(k0_)                                                         \
  {                                                                            \
    _Pragma("unroll") for (int j = 0; j < 4; j++) {                            \
      int idl = 256 * j + t;                                                   \
      int row = idl >> 3, u = idl & 7;                                         \
      ar[j] = *(const uint4*)(A + (size_t)(m0 + row) * 512 + (k0_) + u * 8);   \
      br[j] = *(const uint4*)(Wt + (size_t)(n0 + row) * 512 + (k0_) + u * 8);  \
    }                                                                          \
  }
#define QWRITELDS(buf_)                                                        \
  {                                                                            \
    _Pragma("unroll") for (int j = 0; j < 4; j++) {                            \
      int idl = 256 * j + t;                                                   \
      int row = idl >> 3, u = idl & 7;                                         \
      *(uint4*)&At[buf_][row][u * 8] = ar[j];                                  \
      *(uint4*)&Bt[buf_][row][u * 8] = br[j];                                  \
    }                                                                          \
  }

  QLOADREGS(0);
  QWRITELDS(0);
  __syncthreads();

  for (int it = 0; it < 8; it++) {
    int buf = it & 1;
    if (it < 7) { QLOADREGS((it + 1) * 64); }
#pragma unroll
    for (int kc = 0; kc < 4; kc++) {
      short8 af[2], bf[2];
#pragma unroll
      for (int mt = 0; mt < 2; mt++) af[mt] = *(const short8*)&At[buf][wm + mt * 32 + lq][kc * 16 + hh * 8];
#pragma unroll
      for (int nt = 0; nt < 2; nt++) bf[nt] = *(const short8*)&Bt[buf][wn + nt * 32 + lq][kc * 16 + hh * 8];
#pragma unroll
      for (int mt = 0; mt < 2; mt++)
#pragma unroll
        for (int nt = 0; nt < 2; nt++) {
          if (tr)
            acc[mt][nt] = __builtin_amdgcn_mfma_f32_32x32x16_bf16(bf[nt], af[mt], acc[mt][nt], 0, 0, 0);
          else
            acc[mt][nt] = __builtin_amdgcn_mfma_f32_32x32x16_bf16(af[mt], bf[nt], acc[mt][nt], 0, 0, 0);
        }
    }
    if (it < 7) {
      QWRITELDS(buf ^ 1);
      __syncthreads();
    }
  }
#undef QLOADREGS
#undef QWRITELDS

  if (tr) {
#pragma unroll
    for (int mt = 0; mt < 2; mt++) {
      int token = m0 + wm + mt * 32 + lq;
      int bb = token >> 10, sr = token & 1023;
      int qt = sr >> 5, lqp = sr & 31;
#pragma unroll
      for (int nt = 0; nt < 2; nt++) {
        int nn = n0 + wn + nt * 32;
        int nloc = (nn < 512) ? nn : nn - 512;
        ushort* dst = (nn < 512) ? qf : kf;
        int hd = nloc >> 6;
        int bh = bb * 8 + hd;
        size_t fragbase = ((size_t)(bh * 32 + qt)) * 4 * 512;
#pragma unroll
        for (int rg = 0; rg < 4; rg++) {
          int nbase = nn + rg * 8 + hh * 4;
          float4 bv = *(const float4*)(bias + nbase);
          float v0 = acc[mt][nt][rg * 4 + 0] + bv.x;
          float v1 = acc[mt][nt][rg * 4 + 1] + bv.y;
          float v2 = acc[mt][nt][rg * 4 + 2] + bv.z;
          float v3 = acc[mt][nt][rg * 4 + 3] + bv.w;
          int d0 = (nloc & 63) + rg * 8 + hh * 4;
          size_t addr = fragbase + (size_t)(d0 >> 4) * 512 +
                        (size_t)(((d0 >> 3) & 1) * 32 + lqp) * 8 + (d0 & 7);
          *(uint2*)(dst + addr) = make_uint2(pk_bf16(v0, v1), pk_bf16(v2, v3));
        }
      }
    }
  } else {
#pragma unroll
    for (int nt = 0; nt < 2; nt++) {
      int n = n0 + wn + nt * 32 + lq;
      int nloc = n - 1024;
      int hd = nloc >> 6, d = nloc & 63;
      float bb_ = bias[n];
#pragma unroll
      for (int mt = 0; mt < 2; mt++) {
#pragma unroll
        for (int rg = 0; rg < 4; rg++) {
          int tb = m0 + wm + mt * 32 + rg * 8 + hh * 4;
          int bb = tb >> 10, sr = tb & 1023;
          int bh = bb * 8 + hd;
          float v0 = acc[mt][nt][rg * 4 + 0] + bb_;
          float v1 = acc[mt][nt][rg * 4 + 1] + bb_;
          float v2 = acc[mt][nt][rg * 4 + 2] + bb_;
          float v3 = acc[mt][nt][rg * 4 + 3] + bb_;
          size_t addr = ((size_t)((bh * 2 + (d >> 5)) * 64 + (sr >> 4))) * 512 +
                        (size_t)(((sr >> 3) & 1) * 32 + (d & 31)) * 8 + (sr & 7);
          *(uint2*)(vf + addr) = make_uint2(pk_bf16(v0, v1), pk_bf16(v2, v3));
        }
      }
    }
  }
}

__global__ __launch_bounds__(256, 3) void k_attn(const ushort* __restrict__ qf,
                                                 const ushort* __restrict__ kf,
                                                 const ushort* __restrict__ vf,
                                                 const float* __restrict__ Tl,
                                                 const float* __restrict__ negT,
                                                 const float* __restrict__ Wol,
                                                 float* __restrict__ AOp,
                                                 float* __restrict__ lpart) {
  __shared__ ushort Pt[4][32][72];
  int t = threadIdx.x;
  int w = t >> 6, lane = t & 63;
  int lq = lane & 31, hh = lane >> 5;
  int id = blockIdx.x;
  int bh = id & 31;
  int slot = id >> 5;
  int qtg = slot & 7, j = slot >> 3;
  int b = bh >> 3, head = bh & 7;
  int qt = qtg * 4 + w;
  int q = qt * 32 + lq;
  int kstart = j * 256;

  const ushort* qbase = qf + ((size_t)(bh * 32 + qt)) * 2048 + lane * 8;
  short8 Qf[4];
#pragma unroll
  for (int c = 0; c < 4; c++) Qf[c] = *(const short8*)(qbase + c * 512);

  float Tlo = Tl[1086];
  float Thi = Tl[1024];

  float l_run = 0.f;
  f32x16 Ot[2];
#pragma unroll
  for (int dt = 0; dt < 2; dt++)
#pragma unroll
    for (int i = 0; i < 16; i++) Ot[dt][i] = 0.f;

  for (int it = 0; it < 4; it++) {
    int k0 = kstart + it * 64;
    short8 Kb[2][4];
#pragma unroll
    for (int st = 0; st < 2; st++) {
      const ushort* kb = kf + ((size_t)(bh * 32 + (k0 >> 5) + st)) * 2048 + lane * 8;
#pragma unroll
      for (int c = 0; c < 4; c++) Kb[st][c] = *(const short8*)(kb + c * 512);
    }
    short8 Vb[2][4];
#pragma unroll
    for (int dt = 0; dt < 2; dt++) {
      const ushort* vb = vf + ((size_t)((bh * 2 + dt) * 64 + (k0 >> 4))) * 512 + lane * 8;
#pragma unroll
      for (int c = 0; c < 4; c++) Vb[dt][c] = *(const short8*)(vb + c * 512);
    }
    f32x16 sa[2];
#pragma unroll
    for (int st = 0; st < 2; st++) {
      f32x16 a;
#pragma unroll
      for (int i = 0; i < 16; i++) a[i] = 0.f;
#pragma unroll
      for (int c = 0; c < 4; c++)
        a = __builtin_amdgcn_mfma_f32_32x32x16_bf16(Kb[st][c], Qf[c], a, 0, 0, 0);
      sa[st] = a;
    }
#pragma unroll
    for (int st = 0; st < 2; st++) {
      int kt0 = k0 + st * 32;
      int delta = kt0 - qt * 32;
      if (delta >= 64 || delta <= -64) {
        float bconst = (delta >= 64) ? Tlo : Thi;
#pragma unroll
        for (int rg = 0; rg < 4; rg++) {
          int krun = kt0 + rg * 8 + hh * 4;
          float4 nv = *(const float4*)(negT + b * S_ + krun);
          float p0 = exp2f(fmaf(sa[st][rg * 4 + 0], SCL_, bconst + nv.x));
          float p1 = exp2f(fmaf(sa[st][rg * 4 + 1], SCL_, bconst + nv.y));
          float p2 = exp2f(fmaf(sa[st][rg * 4 + 2], SCL_, bconst + nv.z));
          float p3 = exp2f(fmaf(sa[st][rg * 4 + 3], SCL_, bconst + nv.w));
          l_run += (p0 + p1) + (p2 + p3);
          *(uint2*)&Pt[w][lq][st * 32 + rg * 8 + hh * 4] = make_uint2(pk2(p0, p1), pk2(p2, p3));
        }
      } else {
#pragma unroll
        for (int rg = 0; rg < 4; rg++) {
          int krun = kt0 + rg * 8 + hh * 4;
          float4u bv = *(const float4u*)(Tl + (krun - q + 31 + 1024));
          float4 nv = *(const float4*)(negT + b * S_ + krun);
          float p[4];
#pragma unroll
          for (int i = 0; i < 4; i++) {
            float nvi = (i == 0) ? nv.x : (i == 1) ? nv.y : (i == 2) ? nv.z : nv.w;
            float t0 = (krun + i == q) ? bv[i] : (bv[i] + nvi);
            p[i] = exp2f(fmaf(sa[st][rg * 4 + i], SCL_, t0));
            l_run += p[i];
          }
          *(uint2*)&Pt[w][lq][st * 32 + rg * 8 + hh * 4] = make_uint2(pk2(p[0], p[1]), pk2(p[2], p[3]));
        }
      }
    }
    short8 Pf[4];
#pragma unroll
    for (int c = 0; c < 4; c++) Pf[c] = *(const short8*)&Pt[w][lq][c * 16 + hh * 8];
#pragma unroll
    for (int dt = 0; dt < 2; dt++)
#pragma unroll
      for (int c = 0; c < 4; c++)
        Ot[dt] = __builtin_amdgcn_mfma_f32_32x32x16_bf16(Vb[dt][c], Pf[c], Ot[dt], 0, 0, 0);
  }
  const float* woh = Wol + head * 64 * 4;
  float pe0 = 0.f, pe1 = 0.f, pe2 = 0.f, pe3 = 0.f;
#pragma unroll
  for (int dt = 0; dt < 2; dt++)
#pragma unroll
    for (int rg = 0; rg < 4; rg++)
#pragma unroll
      for (int i = 0; i < 4; i++) {
        int d = dt * 32 + rg * 8 + hh * 4 + i;
        float4 wv = *(const float4*)(woh + d * 4);
        float o = Ot[dt][rg * 4 + i];
        pe0 = fmaf(o, wv.x, pe0);
        pe1 = fmaf(o, wv.y, pe1);
        pe2 = fmaf(o, wv.z, pe2);
        pe3 = fmaf(o, wv.w, pe3);
      }
  pe0 += __shfl_xor(pe0, 32);
  pe1 += __shfl_xor(pe1, 32);
  pe2 += __shfl_xor(pe2, 32);
  pe3 += __shfl_xor(pe3, 32);
  float l_tot = l_run + __shfl_xor(l_run, 32);
  if (hh == 0) {
    float* ao = AOp + (size_t)j * (BS_ * NH_ * 4) + ((size_t)(b * S_ + q) * NH_ + head) * 4;
    *(float4*)ao = make_float4(pe0, pe1, pe2, pe3);
    lpart[((size_t)j * 32 + bh) * S_ + q] = l_tot;
  }
}

__global__ __launch_bounds__(256) void k_resffn(const float* __restrict__ AOp,
                                                const float* __restrict__ lpart,
                                                const float* __restrict__ bo,
                                                const float* __restrict__ g2,
                                                const float* __restrict__ b2n,
                                                const float* __restrict__ Wf1,
                                                const float* __restrict__ bf1,
                                                const float* __restrict__ Wf2,
                                                const float* __restrict__ bf2,
                                                float* __restrict__ x,
                                                const float* __restrict__ Wi,
                                                const float* __restrict__ bi,
                                                const float* __restrict__ g1,
                                                const float* __restrict__ b1n,
                                                ushort* __restrict__ xnbf,
                                                int doinln,
                                                const float* __restrict__ Wout,
                                                const float* __restrict__ bout,
                                                float* __restrict__ out,
                                                int dofinal) {
  int tok = blockIdx.x * 4 + (threadIdx.x >> 6);
  int lane = threadIdx.x & 63;
  int b = tok >> 10, qq = tok & 1023;
  int h = lane & 7;
  int lidx = (b * 8 + h) * 1024 + qq;
  float ls = lpart[lidx] + lpart[lidx + 32768] + lpart[lidx + 65536] + lpart[lidx + 98304];
  float inv = 1.f / ls;
  size_t abase = ((size_t)tok * 8 + h) * 4;
  float4 v0 = *(const float4*)(AOp + abase);
  float4 v1 = *(const float4*)(AOp + abase + 131072);
  float4 v2 = *(const float4*)(AOp + abase + 262144);
  float4 v3 = *(const float4*)(AOp + abase + 393216);
  float r0 = (v0.x + v1.x + v2.x + v3.x) * inv;
  float r1 = (v0.y + v1.y + v2.y + v3.y) * inv;
  float r2 = (v0.z + v1.z + v2.z + v3.z) * inv;
  float r3 = (v0.w + v1.w + v2.w + v3.w) * inv;
#pragma unroll
  for (int o = 1; o < 8; o <<= 1) {
    r0 += __shfl_xor(r0, o); r1 += __shfl_xor(r1, o);
    r2 += __shfl_xor(r2, o); r3 += __shfl_xor(r3, o);
  }
  float4 xo = *(const float4*)&x[tok * 4];
  float x0 = xo.x + r0 + bo[0];
  float x1 = xo.y + r1 + bo[1];
  float x2 = xo.z + r2 + bo[2];
  float x3 = xo.w + r3 + bo[3];
  float mn = 0.25f * (x0 + x1 + x2 + x3);
  float d0 = x0 - mn, d1 = x1 - mn, d2 = x2 - mn, d3 = x3 - mn;
  float var = 0.25f * (d0 * d0 + d1 * d1 + d2 * d2 + d3 * d3);
  float rs = rsqrtf(var + EPS_);
  float l0 = d0 * rs * g2[0] + b2n[0];
  float l1 = d1 * rs * g2[1] + b2n[1];
  float l2 = d2 * rs * g2[2] + b2n[2];
  float l3 = d3 * rs * g2[3] + b2n[3];
  float f0 = 0, f1 = 0, f2 = 0, f3 = 0;
#pragma unroll
  for (int f4 = 0; f4 < FF_ / 64; f4++) {
    int f = lane + f4 * 64;
    float hh = bf1[f] + l0 * Wf1[f] + l1 * Wf1[FF_ + f] + l2 * Wf1[2 * FF_ + f] + l3 * Wf1[3 * FF_ + f];
    hh = fmaxf(hh, 0.f);
    float4 w2 = *(const float4*)&Wf2[f * 4];
    f0 += hh * w2.x; f1 += hh * w2.y; f2 += hh * w2.z; f3 += hh * w2.w;
  }
#pragma unroll
  for (int o = 1; o < 64; o <<= 1) {
    f0 += __shfl_xor(f0, o); f1 += __shfl_xor(f1, o);
    f2 += __shfl_xor(f2, o); f3 += __shfl_xor(f3, o);
  }
  x0 += f0 + bf2[0]; x1 += f1 + bf2[1]; x2 += f2 + bf2[2]; x3 += f3 + bf2[3];
  if (dofinal) {
    if (lane < NT_)
      out[tok * NT_ + lane] = bout[lane] + x0 * Wout[lane] + x1 * Wout[NT_ + lane] +
                              x2 * Wout[2 * NT_ + lane] + x3 * Wout[3 * NT_ + lane];
    return;
  }
  if (lane == 0) *(float4*)&x[tok * 4] = make_float4(x0, x1, x2, x3);
  if (doinln) {
    float xp[8];
    float s = 0.f, qs = 0.f;
#pragma unroll
    for (int k = 0; k < 8; k++) {
      int jj = 64 * k + lane;
      float v = bi[jj] + x0 * Wi[jj] + x1 * Wi[H_ + jj] + x2 * Wi[2 * H_ + jj] + x3 * Wi[3 * H_ + jj];
      xp[k] = v;
      s += v;
      qs += v * v;
    }
#pragma unroll
    for (int o = 1; o < 64; o <<= 1) {
      s += __shfl_xor(s, o);
      qs += __shfl_xor(qs, o);
    }
    float mean = s * (1.f / (float)H_);
    float var1 = qs * (1.f / (float)H_) - mean * mean;
    float rs1 = rsqrtf(var1 + EPS_);
#pragma unroll
    for (int k = 0; k < 8; k++) {
      int jj = 64 * k + lane;
      float v = (xp[k] - mean) * rs1 * g1[jj] + b1n[jj];
      xnbf[tok * H_ + jj] = bf16_rne(v);
    }
  }
}

extern "C" void kernel_launch(void* const* d_in, const int* in_sizes, int n_in,
                              void* d_out, int out_size, void* d_ws, size_t ws_size,
                              hipStream_t stream) {
  const int* patches = (const int*)d_in[0];
  const int* mask = (const int*)d_in[1];
  const float* emb = (const float*)d_in[2];
  const float* Wi = (const float*)d_in[3];
  const float* bi = (const float*)d_in[4];
  const float* Wqkv = (const float*)d_in[5];
  const float* bqkv = (const float*)d_in[6];
  const float* Wo = (const float*)d_in[7];
  const float* bo = (const float*)d_in[8];
  const float* g1 = (const float*)d_in[9];
  const float* b1n = (const float*)d_in[10];
  const float* Wf1 = (const float*)d_in[11];
  const float* bf1 = (const float*)d_in[12];
  const float* Wf2 = (const float*)d_in[13];
  const float* bf2 = (const float*)d_in[14];
  const float* g2 = (const float*)d_in[15];
  const float* b2n = (const float*)d_in[16];
  const float* relemb = (const float*)d_in[17];
  const float* Wout = (const float*)d_in[18];
  const float* bout = (const float*)d_in[19];
  float* out = (float*)d_out;

  char* p = (char*)d_ws;
  float* x = (float*)p;          p += (size_t)BS_ * 4 * 4;
  float* T = (float*)p;          p += (size_t)L_ * 2112 * 4;
  float* negT = (float*)p;       p += (size_t)BS_ * 4;
  float* AOp = (float*)p;        p += (size_t)KSPLIT_ * BS_ * NH_ * 4 * 4;
  float* lpart = (float*)p;      p += (size_t)KSPLIT_ * 32 * 1024 * 4;
  ushort* xnbf = (ushort*)p;     p += (size_t)BS_ * H_ * 2;
  ushort* Wt = (ushort*)p;       p += (size_t)L_ * 1536 * 512 * 2;
  ushort* qf = (ushort*)p;       p += (size_t)32 * 1024 * 64 * 2;
  ushort* kf = (ushort*)p;       p += (size_t)32 * 1024 * 64 * 2;
  ushort* vf = (ushort*)p;       p += (size_t)32 * 64 * 1024 * 2;
  unsigned* bar = (unsigned*)p;  p += 256;

  static int fuse = -1;
  if (fuse < 0) {
    int dev = 0;
    (void)hipGetDevice(&dev);
    int ncu = 0;
    if (hipDeviceGetAttribute(&ncu, hipDeviceAttributeMultiprocessorCount, dev) != hipSuccess) ncu = 0;
    int nb = 0;
    if (hipOccupancyMaxActiveBlocksPerMultiprocessor(&nb, k_fused, 256, 0) != hipSuccess) nb = 0;
    fuse = ((size_t)nb * (size_t)ncu >= GRID_F) ? 1 : 0;
  }

  if (fuse) {
    hipMemsetAsync(bar, 0, 64, stream);  // capture-safe (harness reset() uses memsets)
    FP fp;
    fp.patches = patches; fp.mask = mask; fp.emb = emb; fp.relemb = relemb;
    fp.Wqkv = Wqkv; fp.Wi = Wi; fp.bi = bi; fp.g1 = g1; fp.b1n = b1n;
    fp.bqkv = bqkv; fp.Wo = Wo; fp.bo = bo; fp.g2 = g2; fp.b2n = b2n;
    fp.Wf1 = Wf1; fp.bf1 = bf1; fp.Wf2 = Wf2; fp.bf2 = bf2;
    fp.Wout = Wout; fp.bout = bout;
    fp.x = x; fp.T = T; fp.negT = negT; fp.AOp = AOp; fp.lpart = lpart; fp.out = out;
    fp.xnbf = xnbf; fp.Wt = Wt; fp.qf = qf; fp.kf = kf; fp.vf = vf;
    fp.bar = bar;
    k_fused<<<dim3(GRID_F), dim3(256), 0, stream>>>(fp);
    return;
  }

  k_pre<<<dim3(1841), dim3(256), 0, stream>>>(patches, mask, emb, relemb, Wqkv,
                                              Wi, bi, g1, b1n, x, T, negT, Wt, xnbf);
  for (int l = 0; l < L_; l++) {
    k_qkv<<<dim3(12, 32), dim3(256), 0, stream>>>(xnbf, Wt + (size_t)l * 1536 * 512,
                                                  bqkv + l * 3 * H_, qf, kf, vf);
    k_attn<<<dim3(1024), dim3(256), 0, stream>>>(qf, kf, vf, T + l * 2112, negT,
                                                 Wo + l * H_ * E_, AOp, lpart);
    int nl = l + 1;
    k_resffn<<<dim3(1024), dim3(256), 0, stream>>>(
        AOp, lpart, bo + l * E_, g2 + l * E_, b2n + l * E_,
        Wf1 + l * E_ * FF_, bf1 + l * FF_, Wf2 + l * FF_ * E_, bf2 + l * E_, x,
        Wi + nl * E_ * H_, bi + nl * H_, g1 + nl * H_, b1n + nl * H_, xnbf,
        (l < L_ - 1) ? 1 : 0, Wout, bout, out, (l == L_ - 1) ? 1 : 0);
  }
}

// Round 3
// 315.140 us; speedup vs baseline: 1.0563x; 1.0533x over previous
//
#include <hip/hip_runtime.h>
#include <hip/hip_bf16.h>
#include <math.h>

#define B_ 4
#define S_ 1024
#define H_ 512
#define NH_ 8
#define HD_ 64
#define FF_ 1024
#define E_ 4
#define L_ 4
#define NT_ 17
#define BS_ 4096
#define EPS_ 1e-5f
#define L2E_ 1.4426950408889634f
#define SCL_ 0.18033688011112042f   // 0.125 * log2(e)
#define KSPLIT_ 4

typedef __attribute__((ext_vector_type(8))) short short8;
typedef __attribute__((ext_vector_type(16))) float f32x16;
typedef float float4u __attribute__((ext_vector_type(4), aligned(4)));

__device__ inline ushort bf16_rne(float f) {
  unsigned u = __builtin_bit_cast(unsigned, f);
  u += 0x7FFFu + ((u >> 16) & 1u);
  return (ushort)(u >> 16);
}
__device__ inline unsigned pk_bf16(float a, float b) {
  return (unsigned)bf16_rne(a) | ((unsigned)bf16_rne(b) << 16);
}
// fast pack: round-half-away + v_perm_b32 (3 VALU ops)
__device__ inline unsigned pk2(float a, float b) {
  unsigned ua = __builtin_bit_cast(unsigned, a) + 0x8000u;
  unsigned ub = __builtin_bit_cast(unsigned, b) + 0x8000u;
  return __builtin_amdgcn_perm(ub, ua, 0x07060302u);
}
__device__ inline float ubf2f(ushort u) {
  return __builtin_bit_cast(float, ((unsigned)u) << 16);
}

// ===========================================================================
// R20 journal:
//  - R18/R19: full fusion (cooperative, then software-barrier persistent
//    kernel) measured IDENTICAL to 13-launch (332.9 / 331.9 vs 332.3).
//    => kernel-boundary overhead ~ 0 on this rig; the ~330us is in-phase.
//    Persistent/barrier kernels also break rocprofv3 here (co-residency
//    fails under replay -> spin timeouts -> 90s runs, parse fail).
//    REVERTED to the plain 13-launch pipeline for good.
//  - R20: k_attn occupancy experiment. Was __launch_bounds__(256,3):
//    1024 blocks at 3/CU = 1.33 rounds + 25%-util tail, 3 waves/SIMD.
//    Now (256,4): JIT K/V loads + single sa buffer cut ~64 live VGPRs to
//    fit 128-VGPR budget -> 4 blocks/CU -> 1024 = exactly one round, and
//    4 waves/SIMD latency cover. Same math, same Pt layout (wave-private).
// ===========================================================================

// ---------------------------------------------------------------------------
// k_pre: fused one-time prologue (block-range dispatch).
//   bid in [0,768):     cvtw — Wqkv fp32 -> Wt bf16 [l][n][k] (LDS transpose)
//   bid in [768,817):   init — x/negT/T tables
//   bid in [817,1841):  inln layer 0 — wave/token, direct emb gather
// ---------------------------------------------------------------------------
__global__ __launch_bounds__(256) void k_pre(const int* __restrict__ patches,
                                             const int* __restrict__ mask,
                                             const float* __restrict__ emb,
                                             const float* __restrict__ relemb,
                                             const float* __restrict__ W,
                                             const float* __restrict__ Wi,
                                             const float* __restrict__ bi,
                                             const float* __restrict__ g1,
                                             const float* __restrict__ b1n,
                                             float* __restrict__ x,
                                             float* __restrict__ T,
                                             float* __restrict__ negT,
                                             ushort* __restrict__ Wt,
                                             ushort* __restrict__ xnbf) {
  __shared__ ushort Tr[64][72];
  int bid = blockIdx.x, t = threadIdx.x;
  if (bid < 768) {
    int l = bid / 192, rem = bid % 192;
    int k0 = (rem / 24) * 64, n0 = (rem % 24) * 64;
    const float* src = W + (size_t)l * 512 * 1536;
    int row = t >> 4, c4 = (t & 15) * 4;
#pragma unroll
    for (int rr = 0; rr < 4; rr++) {
      int k = rr * 16 + row;
      float4 v = *(const float4*)(src + (size_t)(k0 + k) * 1536 + n0 + c4);
      Tr[c4 + 0][k] = bf16_rne(v.x);
      Tr[c4 + 1][k] = bf16_rne(v.y);
      Tr[c4 + 2][k] = bf16_rne(v.z);
      Tr[c4 + 3][k] = bf16_rne(v.w);
    }
    __syncthreads();
    int nrow = t >> 2, kc = (t & 3) * 16;
    ushort* dst = Wt + ((size_t)(l * 1536 + n0 + nrow)) * 512 + k0 + kc;
    *(uint4*)dst = *(uint4*)&Tr[nrow][kc];
    *(uint4*)(dst + 8) = *(uint4*)&Tr[nrow][kc + 8];
  } else if (bid < 817) {
    int gid = (bid - 768) * 256 + t;
    if (gid < BS_) {
      int mk = mask[gid];
      int row = mk ? (NT_ - 1) : patches[gid];
      ((float4*)x)[gid] = ((const float4*)emb)[row];
      negT[gid] = mk ? -1e30f : 0.f;
    } else {
      int idx = gid - BS_;
      if (idx < L_ * 2112) {
        int l = idx / 2112, j = idx - l * 2112;
        int c = 1086 - j;
        c = c < 0 ? 0 : (c > 62 ? 62 : c);
        const float* src = relemb + (size_t)(l * 63 + c) * 64;
        float s = 0.f;
#pragma unroll
        for (int d = 0; d < 64; d++) s += src[d];
        T[idx] = s * L2E_;
      }
    }
  } else {
    int token = (bid - 817) * 4 + (t >> 6);
    int lane = t & 63;
    int mk = mask[token];
    int row = mk ? (NT_ - 1) : patches[token];
    float4 e = ((const float4*)emb)[row];
    float xp[8];
    float s = 0.f, qs = 0.f;
#pragma unroll
    for (int k = 0; k < 8; k++) {
      int jj = 64 * k + lane;
      float v = bi[jj] + e.x * Wi[jj] + e.y * Wi[H_ + jj] + e.z * Wi[2 * H_ + jj] + e.w * Wi[3 * H_ + jj];
      xp[k] = v; s += v; qs += v * v;
    }
#pragma unroll
    for (int o = 1; o < 64; o <<= 1) { s += __shfl_xor(s, o); qs += __shfl_xor(qs, o); }
    float mean = s * (1.f / (float)H_);
    float var = qs * (1.f / (float)H_) - mean * mean;
    float rs = rsqrtf(var + EPS_);
#pragma unroll
    for (int k = 0; k < 8; k++) {
      int jj = 64 * k + lane;
      xnbf[token * H_ + jj] = bf16_rne((xp[k] - mean) * rs * g1[jj] + b1n[jj]);
    }
  }
}

// ---------------------------------------------------------------------------
// k_qkv: bf16 MFMA GEMM; 128x128 tile, BK=64.  Register-prefetch + double-
// buffered LDS, one barrier per K-step.  Epilogues write q/k/v frag32.
// ---------------------------------------------------------------------------
__global__ __launch_bounds__(256, 2) void k_qkv(const ushort* __restrict__ A,
                                                const ushort* __restrict__ Wt,
                                                const float* __restrict__ bias,
                                                ushort* __restrict__ qf,
                                                ushort* __restrict__ kf,
                                                ushort* __restrict__ vf) {
  __shared__ ushort At[2][128][72];
  __shared__ ushort Bt[2][128][72];
  int t = threadIdx.x;
  int n0 = blockIdx.x * 128, m0 = blockIdx.y * 128;
  bool tr = (n0 < 1024);
  int w = t >> 6, lq = t & 31, hh = (t >> 5) & 1;
  int wm = (w & 1) * 64, wn = (w >> 1) * 64;
  f32x16 acc[2][2];
#pragma unroll
  for (int mt = 0; mt < 2; mt++)
#pragma unroll
    for (int nt = 0; nt < 2; nt++)
#pragma unroll
      for (int i = 0; i < 16; i++) acc[mt][nt][i] = 0.f;

  uint4 ar[4], br[4];

#define QLOADREGS(k0_)                                                         \
  {                                                                            \
    _Pragma("unroll") for (int j = 0; j < 4; j++) {                            \
      int idl = 256 * j + t;                                                   \
      int row = idl >> 3, u = idl & 7;                                         \
      ar[j] = *(const uint4*)(A + (size_t)(m0 + row) * 512 + (k0_) + u * 8);   \
      br[j] = *(const uint4*)(Wt + (size_t)(n0 + row) * 512 + (k0_) + u * 8);  \
    }                                                                          \
  }
#define QWRITELDS(buf_)                                                        \
  {                                                                            \
    _Pragma("unroll") for (int j = 0; j < 4; j++) {                            \
      int idl = 256 * j + t;                                                   \
      int row = idl >> 3, u = idl & 7;                                         \
      *(uint4*)&At[buf_][row][u * 8] = ar[j];                                  \
      *(uint4*)&Bt[buf_][row][u * 8] = br[j];                                  \
    }                                                                          \
  }

  QLOADREGS(0);
  QWRITELDS(0);
  __syncthreads();

  for (int it = 0; it < 8; it++) {
    int buf = it & 1;
    if (it < 7) { QLOADREGS((it + 1) * 64); }
#pragma unroll
    for (int kc = 0; kc < 4; kc++) {
      short8 af[2], bf[2];
#pragma unroll
      for (int mt = 0; mt < 2; mt++) af[mt] = *(const short8*)&At[buf][wm + mt * 32 + lq][kc * 16 + hh * 8];
#pragma unroll
      for (int nt = 0; nt < 2; nt++) bf[nt] = *(const short8*)&Bt[buf][wn + nt * 32 + lq][kc * 16 + hh * 8];
#pragma unroll
      for (int mt = 0; mt < 2; mt++)
#pragma unroll
        for (int nt = 0; nt < 2; nt++) {
          if (tr)
            acc[mt][nt] = __builtin_amdgcn_mfma_f32_32x32x16_bf16(bf[nt], af[mt], acc[mt][nt], 0, 0, 0);
          else
            acc[mt][nt] = __builtin_amdgcn_mfma_f32_32x32x16_bf16(af[mt], bf[nt], acc[mt][nt], 0, 0, 0);
        }
    }
    if (it < 7) {
      QWRITELDS(buf ^ 1);
      __syncthreads();
    }
  }
#undef QLOADREGS
#undef QWRITELDS

  if (tr) {
#pragma unroll
    for (int mt = 0; mt < 2; mt++) {
      int token = m0 + wm + mt * 32 + lq;
      int bb = token >> 10, sr = token & 1023;
      int qt = sr >> 5, lqp = sr & 31;
#pragma unroll
      for (int nt = 0; nt < 2; nt++) {
        int nn = n0 + wn + nt * 32;
        int nloc = (nn < 512) ? nn : nn - 512;
        ushort* dst = (nn < 512) ? qf : kf;
        int hd = nloc >> 6;
        int bh = bb * 8 + hd;
        size_t fragbase = ((size_t)(bh * 32 + qt)) * 4 * 512;
#pragma unroll
        for (int rg = 0; rg < 4; rg++) {
          int nbase = nn + rg * 8 + hh * 4;
          float4 bv = *(const float4*)(bias + nbase);
          float v0 = acc[mt][nt][rg * 4 + 0] + bv.x;
          float v1 = acc[mt][nt][rg * 4 + 1] + bv.y;
          float v2 = acc[mt][nt][rg * 4 + 2] + bv.z;
          float v3 = acc[mt][nt][rg * 4 + 3] + bv.w;
          int d0 = (nloc & 63) + rg * 8 + hh * 4;
          size_t addr = fragbase + (size_t)(d0 >> 4) * 512 +
                        (size_t)(((d0 >> 3) & 1) * 32 + lqp) * 8 + (d0 & 7);
          *(uint2*)(dst + addr) = make_uint2(pk_bf16(v0, v1), pk_bf16(v2, v3));
        }
      }
    }
  } else {
#pragma unroll
    for (int nt = 0; nt < 2; nt++) {
      int n = n0 + wn + nt * 32 + lq;
      int nloc = n - 1024;
      int hd = nloc >> 6, d = nloc & 63;
      float bb_ = bias[n];
#pragma unroll
      for (int mt = 0; mt < 2; mt++) {
#pragma unroll
        for (int rg = 0; rg < 4; rg++) {
          int tb = m0 + wm + mt * 32 + rg * 8 + hh * 4;
          int bb = tb >> 10, sr = tb & 1023;
          int bh = bb * 8 + hd;
          float v0 = acc[mt][nt][rg * 4 + 0] + bb_;
          float v1 = acc[mt][nt][rg * 4 + 1] + bb_;
          float v2 = acc[mt][nt][rg * 4 + 2] + bb_;
          float v3 = acc[mt][nt][rg * 4 + 3] + bb_;
          size_t addr = ((size_t)((bh * 2 + (d >> 5)) * 64 + (sr >> 4))) * 512 +
                        (size_t)(((sr >> 3) & 1) * 32 + (d & 31)) * 8 + (sr & 7);
          *(uint2*)(vf + addr) = make_uint2(pk_bf16(v0, v1), pk_bf16(v2, v3));
        }
      }
    }
  }
}

// ---------------------------------------------------------------------------
// k_attn: bf16 MFMA attention, S^T form, fixed-scale softmax.
// R20: __launch_bounds__(256,4) -> 4 blocks/CU -> 1024 blocks = ONE full
// round (no tail), 4 waves/SIMD latency cover.  To fit the 128-VGPR budget:
// K loaded just-in-time per st (single sa accumulator), V per dt.  Math is
// unchanged; Pt stays wave-private (no barriers).  Same-bh blocks still map
// to the same XCD (bh = id&31 => id%8 == bh%8) so K/V stay L2-local.
// ---------------------------------------------------------------------------
__global__ __launch_bounds__(256, 4) void k_attn(const ushort* __restrict__ qf,
                                                 const ushort* __restrict__ kf,
                                                 const ushort* __restrict__ vf,
                                                 const float* __restrict__ Tl,
                                                 const float* __restrict__ negT,
                                                 const float* __restrict__ Wol,
                                                 float* __restrict__ AOp,
                                                 float* __restrict__ lpart) {
  __shared__ ushort Pt[4][32][72];
  int t = threadIdx.x;
  int w = t >> 6, lane = t & 63;
  int lq = lane & 31, hh = lane >> 5;
  int id = blockIdx.x;
  int bh = id & 31;
  int slot = id >> 5;
  int qtg = slot & 7, j = slot >> 3;
  int b = bh >> 3, head = bh & 7;
  int qt = qtg * 4 + w;
  int q = qt * 32 + lq;
  int kstart = j * 256;

  const ushort* qbase = qf + ((size_t)(bh * 32 + qt)) * 2048 + lane * 8;
  short8 Qf[4];
#pragma unroll
  for (int c = 0; c < 4; c++) Qf[c] = *(const short8*)(qbase + c * 512);

  float Tlo = Tl[1086];
  float Thi = Tl[1024];

  float l_run = 0.f;
  f32x16 Ot[2];
#pragma unroll
  for (int dt = 0; dt < 2; dt++)
#pragma unroll
    for (int i = 0; i < 16; i++) Ot[dt][i] = 0.f;

  for (int it = 0; it < 4; it++) {
    int k0 = kstart + it * 64;
    // ---- per-st: load K, S^T MFMA, softmax (single live sa buffer) ----
#pragma unroll
    for (int st = 0; st < 2; st++) {
      const ushort* kb = kf + ((size_t)(bh * 32 + (k0 >> 5) + st)) * 2048 + lane * 8;
      short8 Kb[4];
#pragma unroll
      for (int c = 0; c < 4; c++) Kb[c] = *(const short8*)(kb + c * 512);
      f32x16 sa;
#pragma unroll
      for (int i = 0; i < 16; i++) sa[i] = 0.f;
#pragma unroll
      for (int c = 0; c < 4; c++)
        sa = __builtin_amdgcn_mfma_f32_32x32x16_bf16(Kb[c], Qf[c], sa, 0, 0, 0);
      int kt0 = k0 + st * 32;
      int delta = kt0 - qt * 32;
      if (delta >= 64 || delta <= -64) {
        float bconst = (delta >= 64) ? Tlo : Thi;
#pragma unroll
        for (int rg = 0; rg < 4; rg++) {
          int krun = kt0 + rg * 8 + hh * 4;
          float4 nv = *(const float4*)(negT + b * S_ + krun);
          float p0 = exp2f(fmaf(sa[rg * 4 + 0], SCL_, bconst + nv.x));
          float p1 = exp2f(fmaf(sa[rg * 4 + 1], SCL_, bconst + nv.y));
          float p2 = exp2f(fmaf(sa[rg * 4 + 2], SCL_, bconst + nv.z));
          float p3 = exp2f(fmaf(sa[rg * 4 + 3], SCL_, bconst + nv.w));
          l_run += (p0 + p1) + (p2 + p3);
          *(uint2*)&Pt[w][lq][st * 32 + rg * 8 + hh * 4] = make_uint2(pk2(p0, p1), pk2(p2, p3));
        }
      } else {
#pragma unroll
        for (int rg = 0; rg < 4; rg++) {
          int krun = kt0 + rg * 8 + hh * 4;
          float4u bv = *(const float4u*)(Tl + (krun - q + 31 + 1024));
          float4 nv = *(const float4*)(negT + b * S_ + krun);
          float pp[4];
#pragma unroll
          for (int i = 0; i < 4; i++) {
            float nvi = (i == 0) ? nv.x : (i == 1) ? nv.y : (i == 2) ? nv.z : nv.w;
            float t0 = (krun + i == q) ? bv[i] : (bv[i] + nvi);
            pp[i] = exp2f(fmaf(sa[rg * 4 + i], SCL_, t0));
            l_run += pp[i];
          }
          *(uint2*)&Pt[w][lq][st * 32 + rg * 8 + hh * 4] = make_uint2(pk2(pp[0], pp[1]), pk2(pp[2], pp[3]));
        }
      }
    }
    // ---- O^T += V^T . P  (V loaded just-in-time per dt) ----
    short8 Pf[4];
#pragma unroll
    for (int c = 0; c < 4; c++) Pf[c] = *(const short8*)&Pt[w][lq][c * 16 + hh * 8];
#pragma unroll
    for (int dt = 0; dt < 2; dt++) {
      const ushort* vbp = vf + ((size_t)((bh * 2 + dt) * 64 + (k0 >> 4))) * 512 + lane * 8;
      short8 Vb[4];
#pragma unroll
      for (int c = 0; c < 4; c++) Vb[c] = *(const short8*)(vbp + c * 512);
#pragma unroll
      for (int c = 0; c < 4; c++)
        Ot[dt] = __builtin_amdgcn_mfma_f32_32x32x16_bf16(Vb[c], Pf[c], Ot[dt], 0, 0, 0);
    }
  }
  // ---- epilogue: project through Wo[head], store private j-slot partial ----
  const float* woh = Wol + head * 64 * 4;
  float pe0 = 0.f, pe1 = 0.f, pe2 = 0.f, pe3 = 0.f;
#pragma unroll
  for (int dt = 0; dt < 2; dt++)
#pragma unroll
    for (int rg = 0; rg < 4; rg++)
#pragma unroll
      for (int i = 0; i < 4; i++) {
        int d = dt * 32 + rg * 8 + hh * 4 + i;
        float4 wv = *(const float4*)(woh + d * 4);
        float o = Ot[dt][rg * 4 + i];
        pe0 = fmaf(o, wv.x, pe0);
        pe1 = fmaf(o, wv.y, pe1);
        pe2 = fmaf(o, wv.z, pe2);
        pe3 = fmaf(o, wv.w, pe3);
      }
  pe0 += __shfl_xor(pe0, 32);
  pe1 += __shfl_xor(pe1, 32);
  pe2 += __shfl_xor(pe2, 32);
  pe3 += __shfl_xor(pe3, 32);
  float l_tot = l_run + __shfl_xor(l_run, 32);
  if (hh == 0) {
    float* ao = AOp + (size_t)j * (BS_ * NH_ * 4) + ((size_t)(b * S_ + q) * NH_ + head) * 4;
    *(float4*)ao = make_float4(pe0, pe1, pe2, pe3);
    lpart[((size_t)j * 32 + bh) * S_ + q] = l_tot;
  }
}

// ---------------------------------------------------------------------------
// k_resffn: combine j-slot partials per head, sum heads, x += ao + bo,
// ln2(E=4), FFN, residual.  doinln: fuse next layer's inproj+LN.
// dofinal: out = x@Wout+bout.
// ---------------------------------------------------------------------------
__global__ __launch_bounds__(256) void k_resffn(const float* __restrict__ AOp,
                                                const float* __restrict__ lpart,
                                                const float* __restrict__ bo,
                                                const float* __restrict__ g2,
                                                const float* __restrict__ b2n,
                                                const float* __restrict__ Wf1,
                                                const float* __restrict__ bf1,
                                                const float* __restrict__ Wf2,
                                                const float* __restrict__ bf2,
                                                float* __restrict__ x,
                                                const float* __restrict__ Wi,
                                                const float* __restrict__ bi,
                                                const float* __restrict__ g1,
                                                const float* __restrict__ b1n,
                                                ushort* __restrict__ xnbf,
                                                int doinln,
                                                const float* __restrict__ Wout,
                                                const float* __restrict__ bout,
                                                float* __restrict__ out,
                                                int dofinal) {
  int tok = blockIdx.x * 4 + (threadIdx.x >> 6);
  int lane = threadIdx.x & 63;
  int b = tok >> 10, qq = tok & 1023;
  int h = lane & 7;
  int lidx = (b * 8 + h) * 1024 + qq;
  float ls = lpart[lidx] + lpart[lidx + 32768] + lpart[lidx + 65536] + lpart[lidx + 98304];
  float inv = 1.f / ls;
  size_t abase = ((size_t)tok * 8 + h) * 4;
  float4 v0 = *(const float4*)(AOp + abase);
  float4 v1 = *(const float4*)(AOp + abase + 131072);
  float4 v2 = *(const float4*)(AOp + abase + 262144);
  float4 v3 = *(const float4*)(AOp + abase + 393216);
  float r0 = (v0.x + v1.x + v2.x + v3.x) * inv;
  float r1 = (v0.y + v1.y + v2.y + v3.y) * inv;
  float r2 = (v0.z + v1.z + v2.z + v3.z) * inv;
  float r3 = (v0.w + v1.w + v2.w + v3.w) * inv;
#pragma unroll
  for (int o = 1; o < 8; o <<= 1) {
    r0 += __shfl_xor(r0, o); r1 += __shfl_xor(r1, o);
    r2 += __shfl_xor(r2, o); r3 += __shfl_xor(r3, o);
  }
  float4 xo = *(const float4*)&x[tok * 4];
  float x0 = xo.x + r0 + bo[0];
  float x1 = xo.y + r1 + bo[1];
  float x2 = xo.z + r2 + bo[2];
  float x3 = xo.w + r3 + bo[3];
  float mn = 0.25f * (x0 + x1 + x2 + x3);
  float d0 = x0 - mn, d1 = x1 - mn, d2 = x2 - mn, d3 = x3 - mn;
  float var = 0.25f * (d0 * d0 + d1 * d1 + d2 * d2 + d3 * d3);
  float rs = rsqrtf(var + EPS_);
  float l0 = d0 * rs * g2[0] + b2n[0];
  float l1 = d1 * rs * g2[1] + b2n[1];
  float l2 = d2 * rs * g2[2] + b2n[2];
  float l3 = d3 * rs * g2[3] + b2n[3];
  float f0 = 0, f1 = 0, f2 = 0, f3 = 0;
#pragma unroll
  for (int f4 = 0; f4 < FF_ / 64; f4++) {
    int f = lane + f4 * 64;
    float hh = bf1[f] + l0 * Wf1[f] + l1 * Wf1[FF_ + f] + l2 * Wf1[2 * FF_ + f] + l3 * Wf1[3 * FF_ + f];
    hh = fmaxf(hh, 0.f);
    float4 w2 = *(const float4*)&Wf2[f * 4];
    f0 += hh * w2.x; f1 += hh * w2.y; f2 += hh * w2.z; f3 += hh * w2.w;
  }
#pragma unroll
  for (int o = 1; o < 64; o <<= 1) {
    f0 += __shfl_xor(f0, o); f1 += __shfl_xor(f1, o);
    f2 += __shfl_xor(f2, o); f3 += __shfl_xor(f3, o);
  }
  x0 += f0 + bf2[0]; x1 += f1 + bf2[1]; x2 += f2 + bf2[2]; x3 += f3 + bf2[3];
  if (dofinal) {
    if (lane < NT_)
      out[tok * NT_ + lane] = bout[lane] + x0 * Wout[lane] + x1 * Wout[NT_ + lane] +
                              x2 * Wout[2 * NT_ + lane] + x3 * Wout[3 * NT_ + lane];
    return;
  }
  if (lane == 0) *(float4*)&x[tok * 4] = make_float4(x0, x1, x2, x3);
  if (doinln) {
    float xp[8];
    float s = 0.f, qs = 0.f;
#pragma unroll
    for (int k = 0; k < 8; k++) {
      int jj = 64 * k + lane;
      float v = bi[jj] + x0 * Wi[jj] + x1 * Wi[H_ + jj] + x2 * Wi[2 * H_ + jj] + x3 * Wi[3 * H_ + jj];
      xp[k] = v;
      s += v;
      qs += v * v;
    }
#pragma unroll
    for (int o = 1; o < 64; o <<= 1) {
      s += __shfl_xor(s, o);
      qs += __shfl_xor(qs, o);
    }
    float mean = s * (1.f / (float)H_);
    float var1 = qs * (1.f / (float)H_) - mean * mean;
    float rs1 = rsqrtf(var1 + EPS_);
#pragma unroll
    for (int k = 0; k < 8; k++) {
      int jj = 64 * k + lane;
      float v = (xp[k] - mean) * rs1 * g1[jj] + b1n[jj];
      xnbf[tok * H_ + jj] = bf16_rne(v);
    }
  }
}

extern "C" void kernel_launch(void* const* d_in, const int* in_sizes, int n_in,
                              void* d_out, int out_size, void* d_ws, size_t ws_size,
                              hipStream_t stream) {
  const int* patches = (const int*)d_in[0];
  const int* mask = (const int*)d_in[1];
  const float* emb = (const float*)d_in[2];
  const float* Wi = (const float*)d_in[3];
  const float* bi = (const float*)d_in[4];
  const float* Wqkv = (const float*)d_in[5];
  const float* bqkv = (const float*)d_in[6];
  const float* Wo = (const float*)d_in[7];
  const float* bo = (const float*)d_in[8];
  const float* g1 = (const float*)d_in[9];
  const float* b1n = (const float*)d_in[10];
  const float* Wf1 = (const float*)d_in[11];
  const float* bf1 = (const float*)d_in[12];
  const float* Wf2 = (const float*)d_in[13];
  const float* bf2 = (const float*)d_in[14];
  const float* g2 = (const float*)d_in[15];
  const float* b2n = (const float*)d_in[16];
  const float* relemb = (const float*)d_in[17];
  const float* Wout = (const float*)d_in[18];
  const float* bout = (const float*)d_in[19];
  float* out = (float*)d_out;

  char* p = (char*)d_ws;
  float* x = (float*)p;          p += (size_t)BS_ * 4 * 4;
  float* T = (float*)p;          p += (size_t)L_ * 2112 * 4;
  float* negT = (float*)p;       p += (size_t)BS_ * 4;
  float* AOp = (float*)p;        p += (size_t)KSPLIT_ * BS_ * NH_ * 4 * 4;
  float* lpart = (float*)p;      p += (size_t)KSPLIT_ * 32 * 1024 * 4;
  ushort* xnbf = (ushort*)p;     p += (size_t)BS_ * H_ * 2;
  ushort* Wt = (ushort*)p;       p += (size_t)L_ * 1536 * 512 * 2;
  ushort* qf = (ushort*)p;       p += (size_t)32 * 1024 * 64 * 2;
  ushort* kf = (ushort*)p;       p += (size_t)32 * 1024 * 64 * 2;
  ushort* vf = (ushort*)p;       p += (size_t)32 * 64 * 1024 * 2;

  k_pre<<<dim3(1841), dim3(256), 0, stream>>>(patches, mask, emb, relemb, Wqkv,
                                              Wi, bi, g1, b1n, x, T, negT, Wt, xnbf);
  for (int l = 0; l < L_; l++) {
    k_qkv<<<dim3(12, 32), dim3(256), 0, stream>>>(xnbf, Wt + (size_t)l * 1536 * 512,
                                                  bqkv + l * 3 * H_, qf, kf, vf);
    k_attn<<<dim3(1024), dim3(256), 0, stream>>>(qf, kf, vf, T + l * 2112, negT,
                                                 Wo + l * H_ * E_, AOp, lpart);
    int nl = l + 1;
    k_resffn<<<dim3(1024), dim3(256), 0, stream>>>(
        AOp, lpart, bo + l * E_, g2 + l * E_, b2n + l * E_,
        Wf1 + l * E_ * FF_, bf1 + l * FF_, Wf2 + l * FF_ * E_, bf2 + l * E_, x,
        Wi + nl * E_ * H_, bi + nl * H_, g1 + nl * H_, b1n + nl * H_, xnbf,
        (l < L_ - 1) ? 1 : 0, Wout, bout, out, (l == L_ - 1) ? 1 : 0);
  }
}

// Round 4
// 299.167 us; speedup vs baseline: 1.1127x; 1.0534x over previous
//
#include <hip/hip_runtime.h>
#include <hip/hip_bf16.h>
#include <math.h>

#define B_ 4
#define S_ 1024
#define H_ 512
#define NH_ 8
#define HD_ 64
#define FF_ 1024
#define E_ 4
#define L_ 4
#define NT_ 17
#define BS_ 4096
#define EPS_ 1e-5f
#define L2E_ 1.4426950408889634f
#define SCL_ 0.18033688011112042f   // 0.125 * log2(e)
#define KSPLIT_ 4

typedef __attribute__((ext_vector_type(8))) short short8;
typedef __attribute__((ext_vector_type(16))) float f32x16;
typedef float float4u __attribute__((ext_vector_type(4), aligned(4)));

__device__ inline ushort bf16_rne(float f) {
  unsigned u = __builtin_bit_cast(unsigned, f);
  u += 0x7FFFu + ((u >> 16) & 1u);
  return (ushort)(u >> 16);
}
__device__ inline unsigned pk_bf16(float a, float b) {
  return (unsigned)bf16_rne(a) | ((unsigned)bf16_rne(b) << 16);
}
// fast pack: round-half-away + v_perm_b32 (3 VALU ops)
__device__ inline unsigned pk2(float a, float b) {
  unsigned ua = __builtin_bit_cast(unsigned, a) + 0x8000u;
  unsigned ub = __builtin_bit_cast(unsigned, b) + 0x8000u;
  return __builtin_amdgcn_perm(ub, ua, 0x07060302u);
}
__device__ inline float ubf2f(ushort u) {
  return __builtin_bit_cast(float, ((unsigned)u) << 16);
}

// ===========================================================================
// Journal:
//  - R18/R19: full fusion (cooperative / software-barrier persistent kernel)
//    measured IDENTICAL to 13-launch (332.9 / 331.9 vs 332.3) => kernel-
//    boundary overhead ~0 on this rig; persistent kernels also break
//    rocprofv3 (replay breaks co-residency). 13-launch structure is final.
//  - R20 WIN: k_attn (256,3)->(256,4) via JIT K/V loads: 1024 blocks = one
//    full round, 4 waves/SIMD. 332 -> 315.1us (-17, ~4.3us/layer). The
//    latency-cover model is confirmed as the right lens.
//  - R21: k_qkv was the TLP floor: 384 blocks x 4 waves = 1536 waves =
//    1.5 waves/SIMD machine-wide. Same tile/LDS/barrier structure, but
//    8 waves/block (512 thr), wave grid 2Mx4N, acc[2] (64x32/wave) ->
//    3072 waves = 3 waves/SIMD, half the staging work per thread.
// ===========================================================================

// ---------------------------------------------------------------------------
// k_pre: fused one-time prologue (block-range dispatch).
//   bid in [0,768):     cvtw — Wqkv fp32 -> Wt bf16 [l][n][k] (LDS transpose)
//   bid in [768,817):   init — x/negT/T tables
//   bid in [817,1841):  inln layer 0 — wave/token, direct emb gather
// ---------------------------------------------------------------------------
__global__ __launch_bounds__(256) void k_pre(const int* __restrict__ patches,
                                             const int* __restrict__ mask,
                                             const float* __restrict__ emb,
                                             const float* __restrict__ relemb,
                                             const float* __restrict__ W,
                                             const float* __restrict__ Wi,
                                             const float* __restrict__ bi,
                                             const float* __restrict__ g1,
                                             const float* __restrict__ b1n,
                                             float* __restrict__ x,
                                             float* __restrict__ T,
                                             float* __restrict__ negT,
                                             ushort* __restrict__ Wt,
                                             ushort* __restrict__ xnbf) {
  __shared__ ushort Tr[64][72];
  int bid = blockIdx.x, t = threadIdx.x;
  if (bid < 768) {
    int l = bid / 192, rem = bid % 192;
    int k0 = (rem / 24) * 64, n0 = (rem % 24) * 64;
    const float* src = W + (size_t)l * 512 * 1536;
    int row = t >> 4, c4 = (t & 15) * 4;
#pragma unroll
    for (int rr = 0; rr < 4; rr++) {
      int k = rr * 16 + row;
      float4 v = *(const float4*)(src + (size_t)(k0 + k) * 1536 + n0 + c4);
      Tr[c4 + 0][k] = bf16_rne(v.x);
      Tr[c4 + 1][k] = bf16_rne(v.y);
      Tr[c4 + 2][k] = bf16_rne(v.z);
      Tr[c4 + 3][k] = bf16_rne(v.w);
    }
    __syncthreads();
    int nrow = t >> 2, kc = (t & 3) * 16;
    ushort* dst = Wt + ((size_t)(l * 1536 + n0 + nrow)) * 512 + k0 + kc;
    *(uint4*)dst = *(uint4*)&Tr[nrow][kc];
    *(uint4*)(dst + 8) = *(uint4*)&Tr[nrow][kc + 8];
  } else if (bid < 817) {
    int gid = (bid - 768) * 256 + t;
    if (gid < BS_) {
      int mk = mask[gid];
      int row = mk ? (NT_ - 1) : patches[gid];
      ((float4*)x)[gid] = ((const float4*)emb)[row];
      negT[gid] = mk ? -1e30f : 0.f;
    } else {
      int idx = gid - BS_;
      if (idx < L_ * 2112) {
        int l = idx / 2112, j = idx - l * 2112;
        int c = 1086 - j;
        c = c < 0 ? 0 : (c > 62 ? 62 : c);
        const float* src = relemb + (size_t)(l * 63 + c) * 64;
        float s = 0.f;
#pragma unroll
        for (int d = 0; d < 64; d++) s += src[d];
        T[idx] = s * L2E_;
      }
    }
  } else {
    int token = (bid - 817) * 4 + (t >> 6);
    int lane = t & 63;
    int mk = mask[token];
    int row = mk ? (NT_ - 1) : patches[token];
    float4 e = ((const float4*)emb)[row];
    float xp[8];
    float s = 0.f, qs = 0.f;
#pragma unroll
    for (int k = 0; k < 8; k++) {
      int jj = 64 * k + lane;
      float v = bi[jj] + e.x * Wi[jj] + e.y * Wi[H_ + jj] + e.z * Wi[2 * H_ + jj] + e.w * Wi[3 * H_ + jj];
      xp[k] = v; s += v; qs += v * v;
    }
#pragma unroll
    for (int o = 1; o < 64; o <<= 1) { s += __shfl_xor(s, o); qs += __shfl_xor(qs, o); }
    float mean = s * (1.f / (float)H_);
    float var = qs * (1.f / (float)H_) - mean * mean;
    float rs = rsqrtf(var + EPS_);
#pragma unroll
    for (int k = 0; k < 8; k++) {
      int jj = 64 * k + lane;
      xnbf[token * H_ + jj] = bf16_rne((xp[k] - mean) * rs * g1[jj] + b1n[jj]);
    }
  }
}

// ---------------------------------------------------------------------------
// k_qkv: bf16 MFMA GEMM; 128x128 tile, BK=64.  Register-prefetch + double-
// buffered LDS, one barrier per K-step.  R21: 8 waves/block (512 thr),
// wave grid 2Mx4N, 64x32 output per wave -> 3072 waves (3/SIMD) vs the old
// 1536 (1.5/SIMD).  Same math / LDS / barrier structure; epilogue nt-loop
// collapsed (each wave owns one 32-wide N sub-tile).
// ---------------------------------------------------------------------------
__global__ __launch_bounds__(512, 4) void k_qkv(const ushort* __restrict__ A,
                                                const ushort* __restrict__ Wt,
                                                const float* __restrict__ bias,
                                                ushort* __restrict__ qf,
                                                ushort* __restrict__ kf,
                                                ushort* __restrict__ vf) {
  __shared__ ushort At[2][128][72];
  __shared__ ushort Bt[2][128][72];
  int t = threadIdx.x;
  int n0 = blockIdx.x * 128, m0 = blockIdx.y * 128;
  bool tr = (n0 < 1024);
  int w = t >> 6, lq = t & 31, hh = (t >> 5) & 1;
  int wm = (w & 1) * 64, wn = (w >> 1) * 32;
  f32x16 acc[2];
#pragma unroll
  for (int mt = 0; mt < 2; mt++)
#pragma unroll
    for (int i = 0; i < 16; i++) acc[mt][i] = 0.f;

  uint4 ar[2], br[2];

#define QLOADREGS(k0_)                                                         \
  {                                                                            \
    _Pragma("unroll") for (int j = 0; j < 2; j++) {                            \
      int idl = 512 * j + t;                                                   \
      int row = idl >> 3, u = idl & 7;                                         \
      ar[j] = *(const uint4*)(A + (size_t)(m0 + row) * 512 + (k0_) + u * 8);   \
      br[j] = *(const uint4*)(Wt + (size_t)(n0 + row) * 512 + (k0_) + u * 8);  \
    }                                                                          \
  }
#define QWRITELDS(buf_)                                                        \
  {                                                                            \
    _Pragma("unroll") for (int j = 0; j < 2; j++) {                            \
      int idl = 512 * j + t;                                                   \
      int row = idl >> 3, u = idl & 7;                                         \
      *(uint4*)&At[buf_][row][u * 8] = ar[j];                                  \
      *(uint4*)&Bt[buf_][row][u * 8] = br[j];                                  \
    }                                                                          \
  }

  QLOADREGS(0);
  QWRITELDS(0);
  __syncthreads();

  for (int it = 0; it < 8; it++) {
    int buf = it & 1;
    if (it < 7) { QLOADREGS((it + 1) * 64); }
#pragma unroll
    for (int kc = 0; kc < 4; kc++) {
      short8 af[2], bf;
#pragma unroll
      for (int mt = 0; mt < 2; mt++) af[mt] = *(const short8*)&At[buf][wm + mt * 32 + lq][kc * 16 + hh * 8];
      bf = *(const short8*)&Bt[buf][wn + lq][kc * 16 + hh * 8];
#pragma unroll
      for (int mt = 0; mt < 2; mt++) {
        if (tr)
          acc[mt] = __builtin_amdgcn_mfma_f32_32x32x16_bf16(bf, af[mt], acc[mt], 0, 0, 0);
        else
          acc[mt] = __builtin_amdgcn_mfma_f32_32x32x16_bf16(af[mt], bf, acc[mt], 0, 0, 0);
      }
    }
    if (it < 7) {
      QWRITELDS(buf ^ 1);
      __syncthreads();
    }
  }
#undef QLOADREGS
#undef QWRITELDS

  if (tr) {
#pragma unroll
    for (int mt = 0; mt < 2; mt++) {
      int token = m0 + wm + mt * 32 + lq;
      int bb = token >> 10, sr = token & 1023;
      int qt = sr >> 5, lqp = sr & 31;
      int nn = n0 + wn;
      int nloc = (nn < 512) ? nn : nn - 512;
      ushort* dst = (nn < 512) ? qf : kf;
      int hd = nloc >> 6;
      int bh = bb * 8 + hd;
      size_t fragbase = ((size_t)(bh * 32 + qt)) * 4 * 512;
#pragma unroll
      for (int rg = 0; rg < 4; rg++) {
        int nbase = nn + rg * 8 + hh * 4;
        float4 bv = *(const float4*)(bias + nbase);
        float v0 = acc[mt][rg * 4 + 0] + bv.x;
        float v1 = acc[mt][rg * 4 + 1] + bv.y;
        float v2 = acc[mt][rg * 4 + 2] + bv.z;
        float v3 = acc[mt][rg * 4 + 3] + bv.w;
        int d0 = (nloc & 63) + rg * 8 + hh * 4;
        size_t addr = fragbase + (size_t)(d0 >> 4) * 512 +
                      (size_t)(((d0 >> 3) & 1) * 32 + lqp) * 8 + (d0 & 7);
        *(uint2*)(dst + addr) = make_uint2(pk_bf16(v0, v1), pk_bf16(v2, v3));
      }
    }
  } else {
    int n = n0 + wn + lq;
    int nloc = n - 1024;
    int hd = nloc >> 6, d = nloc & 63;
    float bb_ = bias[n];
#pragma unroll
    for (int mt = 0; mt < 2; mt++) {
#pragma unroll
      for (int rg = 0; rg < 4; rg++) {
        int tb = m0 + wm + mt * 32 + rg * 8 + hh * 4;
        int bb = tb >> 10, sr = tb & 1023;
        int bh = bb * 8 + hd;
        float v0 = acc[mt][rg * 4 + 0] + bb_;
        float v1 = acc[mt][rg * 4 + 1] + bb_;
        float v2 = acc[mt][rg * 4 + 2] + bb_;
        float v3 = acc[mt][rg * 4 + 3] + bb_;
        size_t addr = ((size_t)((bh * 2 + (d >> 5)) * 64 + (sr >> 4))) * 512 +
                      (size_t)(((sr >> 3) & 1) * 32 + (d & 31)) * 8 + (sr & 7);
        *(uint2*)(vf + addr) = make_uint2(pk_bf16(v0, v1), pk_bf16(v2, v3));
      }
    }
  }
}

// ---------------------------------------------------------------------------
// k_attn: bf16 MFMA attention, S^T form, fixed-scale softmax.
// R20: __launch_bounds__(256,4) -> 4 blocks/CU -> 1024 blocks = ONE full
// round (no tail), 4 waves/SIMD latency cover.  K loaded just-in-time per
// st (single sa accumulator), V per dt.  Pt stays wave-private.
// ---------------------------------------------------------------------------
__global__ __launch_bounds__(256, 4) void k_attn(const ushort* __restrict__ qf,
                                                 const ushort* __restrict__ kf,
                                                 const ushort* __restrict__ vf,
                                                 const float* __restrict__ Tl,
                                                 const float* __restrict__ negT,
                                                 const float* __restrict__ Wol,
                                                 float* __restrict__ AOp,
                                                 float* __restrict__ lpart) {
  __shared__ ushort Pt[4][32][72];
  int t = threadIdx.x;
  int w = t >> 6, lane = t & 63;
  int lq = lane & 31, hh = lane >> 5;
  int id = blockIdx.x;
  int bh = id & 31;
  int slot = id >> 5;
  int qtg = slot & 7, j = slot >> 3;
  int b = bh >> 3, head = bh & 7;
  int qt = qtg * 4 + w;
  int q = qt * 32 + lq;
  int kstart = j * 256;

  const ushort* qbase = qf + ((size_t)(bh * 32 + qt)) * 2048 + lane * 8;
  short8 Qf[4];
#pragma unroll
  for (int c = 0; c < 4; c++) Qf[c] = *(const short8*)(qbase + c * 512);

  float Tlo = Tl[1086];
  float Thi = Tl[1024];

  float l_run = 0.f;
  f32x16 Ot[2];
#pragma unroll
  for (int dt = 0; dt < 2; dt++)
#pragma unroll
    for (int i = 0; i < 16; i++) Ot[dt][i] = 0.f;

  for (int it = 0; it < 4; it++) {
    int k0 = kstart + it * 64;
    // ---- per-st: load K, S^T MFMA, softmax (single live sa buffer) ----
#pragma unroll
    for (int st = 0; st < 2; st++) {
      const ushort* kb = kf + ((size_t)(bh * 32 + (k0 >> 5) + st)) * 2048 + lane * 8;
      short8 Kb[4];
#pragma unroll
      for (int c = 0; c < 4; c++) Kb[c] = *(const short8*)(kb + c * 512);
      f32x16 sa;
#pragma unroll
      for (int i = 0; i < 16; i++) sa[i] = 0.f;
#pragma unroll
      for (int c = 0; c < 4; c++)
        sa = __builtin_amdgcn_mfma_f32_32x32x16_bf16(Kb[c], Qf[c], sa, 0, 0, 0);
      int kt0 = k0 + st * 32;
      int delta = kt0 - qt * 32;
      if (delta >= 64 || delta <= -64) {
        float bconst = (delta >= 64) ? Tlo : Thi;
#pragma unroll
        for (int rg = 0; rg < 4; rg++) {
          int krun = kt0 + rg * 8 + hh * 4;
          float4 nv = *(const float4*)(negT + b * S_ + krun);
          float p0 = exp2f(fmaf(sa[rg * 4 + 0], SCL_, bconst + nv.x));
          float p1 = exp2f(fmaf(sa[rg * 4 + 1], SCL_, bconst + nv.y));
          float p2 = exp2f(fmaf(sa[rg * 4 + 2], SCL_, bconst + nv.z));
          float p3 = exp2f(fmaf(sa[rg * 4 + 3], SCL_, bconst + nv.w));
          l_run += (p0 + p1) + (p2 + p3);
          *(uint2*)&Pt[w][lq][st * 32 + rg * 8 + hh * 4] = make_uint2(pk2(p0, p1), pk2(p2, p3));
        }
      } else {
#pragma unroll
        for (int rg = 0; rg < 4; rg++) {
          int krun = kt0 + rg * 8 + hh * 4;
          float4u bv = *(const float4u*)(Tl + (krun - q + 31 + 1024));
          float4 nv = *(const float4*)(negT + b * S_ + krun);
          float pp[4];
#pragma unroll
          for (int i = 0; i < 4; i++) {
            float nvi = (i == 0) ? nv.x : (i == 1) ? nv.y : (i == 2) ? nv.z : nv.w;
            float t0 = (krun + i == q) ? bv[i] : (bv[i] + nvi);
            pp[i] = exp2f(fmaf(sa[rg * 4 + i], SCL_, t0));
            l_run += pp[i];
          }
          *(uint2*)&Pt[w][lq][st * 32 + rg * 8 + hh * 4] = make_uint2(pk2(pp[0], pp[1]), pk2(pp[2], pp[3]));
        }
      }
    }
    // ---- O^T += V^T . P  (V loaded just-in-time per dt) ----
    short8 Pf[4];
#pragma unroll
    for (int c = 0; c < 4; c++) Pf[c] = *(const short8*)&Pt[w][lq][c * 16 + hh * 8];
#pragma unroll
    for (int dt = 0; dt < 2; dt++) {
      const ushort* vbp = vf + ((size_t)((bh * 2 + dt) * 64 + (k0 >> 4))) * 512 + lane * 8;
      short8 Vb[4];
#pragma unroll
      for (int c = 0; c < 4; c++) Vb[c] = *(const short8*)(vbp + c * 512);
#pragma unroll
      for (int c = 0; c < 4; c++)
        Ot[dt] = __builtin_amdgcn_mfma_f32_32x32x16_bf16(Vb[c], Pf[c], Ot[dt], 0, 0, 0);
    }
  }
  // ---- epilogue: project through Wo[head], store private j-slot partial ----
  const float* woh = Wol + head * 64 * 4;
  float pe0 = 0.f, pe1 = 0.f, pe2 = 0.f, pe3 = 0.f;
#pragma unroll
  for (int dt = 0; dt < 2; dt++)
#pragma unroll
    for (int rg = 0; rg < 4; rg++)
#pragma unroll
      for (int i = 0; i < 4; i++) {
        int d = dt * 32 + rg * 8 + hh * 4 + i;
        float4 wv = *(const float4*)(woh + d * 4);
        float o = Ot[dt][rg * 4 + i];
        pe0 = fmaf(o, wv.x, pe0);
        pe1 = fmaf(o, wv.y, pe1);
        pe2 = fmaf(o, wv.z, pe2);
        pe3 = fmaf(o, wv.w, pe3);
      }
  pe0 += __shfl_xor(pe0, 32);
  pe1 += __shfl_xor(pe1, 32);
  pe2 += __shfl_xor(pe2, 32);
  pe3 += __shfl_xor(pe3, 32);
  float l_tot = l_run + __shfl_xor(l_run, 32);
  if (hh == 0) {
    float* ao = AOp + (size_t)j * (BS_ * NH_ * 4) + ((size_t)(b * S_ + q) * NH_ + head) * 4;
    *(float4*)ao = make_float4(pe0, pe1, pe2, pe3);
    lpart[((size_t)j * 32 + bh) * S_ + q] = l_tot;
  }
}

// ---------------------------------------------------------------------------
// k_resffn: combine j-slot partials per head, sum heads, x += ao + bo,
// ln2(E=4), FFN, residual.  doinln: fuse next layer's inproj+LN.
// dofinal: out = x@Wout+bout.
// ---------------------------------------------------------------------------
__global__ __launch_bounds__(256) void k_resffn(const float* __restrict__ AOp,
                                                const float* __restrict__ lpart,
                                                const float* __restrict__ bo,
                                                const float* __restrict__ g2,
                                                const float* __restrict__ b2n,
                                                const float* __restrict__ Wf1,
                                                const float* __restrict__ bf1,
                                                const float* __restrict__ Wf2,
                                                const float* __restrict__ bf2,
                                                float* __restrict__ x,
                                                const float* __restrict__ Wi,
                                                const float* __restrict__ bi,
                                                const float* __restrict__ g1,
                                                const float* __restrict__ b1n,
                                                ushort* __restrict__ xnbf,
                                                int doinln,
                                                const float* __restrict__ Wout,
                                                const float* __restrict__ bout,
                                                float* __restrict__ out,
                                                int dofinal) {
  int tok = blockIdx.x * 4 + (threadIdx.x >> 6);
  int lane = threadIdx.x & 63;
  int b = tok >> 10, qq = tok & 1023;
  int h = lane & 7;
  int lidx = (b * 8 + h) * 1024 + qq;
  float ls = lpart[lidx] + lpart[lidx + 32768] + lpart[lidx + 65536] + lpart[lidx + 98304];
  float inv = 1.f / ls;
  size_t abase = ((size_t)tok * 8 + h) * 4;
  float4 v0 = *(const float4*)(AOp + abase);
  float4 v1 = *(const float4*)(AOp + abase + 131072);
  float4 v2 = *(const float4*)(AOp + abase + 262144);
  float4 v3 = *(const float4*)(AOp + abase + 393216);
  float r0 = (v0.x + v1.x + v2.x + v3.x) * inv;
  float r1 = (v0.y + v1.y + v2.y + v3.y) * inv;
  float r2 = (v0.z + v1.z + v2.z + v3.z) * inv;
  float r3 = (v0.w + v1.w + v2.w + v3.w) * inv;
#pragma unroll
  for (int o = 1; o < 8; o <<= 1) {
    r0 += __shfl_xor(r0, o); r1 += __shfl_xor(r1, o);
    r2 += __shfl_xor(r2, o); r3 += __shfl_xor(r3, o);
  }
  float4 xo = *(const float4*)&x[tok * 4];
  float x0 = xo.x + r0 + bo[0];
  float x1 = xo.y + r1 + bo[1];
  float x2 = xo.z + r2 + bo[2];
  float x3 = xo.w + r3 + bo[3];
  float mn = 0.25f * (x0 + x1 + x2 + x3);
  float d0 = x0 - mn, d1 = x1 - mn, d2 = x2 - mn, d3 = x3 - mn;
  float var = 0.25f * (d0 * d0 + d1 * d1 + d2 * d2 + d3 * d3);
  float rs = rsqrtf(var + EPS_);
  float l0 = d0 * rs * g2[0] + b2n[0];
  float l1 = d1 * rs * g2[1] + b2n[1];
  float l2 = d2 * rs * g2[2] + b2n[2];
  float l3 = d3 * rs * g2[3] + b2n[3];
  float f0 = 0, f1 = 0, f2 = 0, f3 = 0;
#pragma unroll
  for (int f4 = 0; f4 < FF_ / 64; f4++) {
    int f = lane + f4 * 64;
    float hh = bf1[f] + l0 * Wf1[f] + l1 * Wf1[FF_ + f] + l2 * Wf1[2 * FF_ + f] + l3 * Wf1[3 * FF_ + f];
    hh = fmaxf(hh, 0.f);
    float4 w2 = *(const float4*)&Wf2[f * 4];
    f0 += hh * w2.x; f1 += hh * w2.y; f2 += hh * w2.z; f3 += hh * w2.w;
  }
#pragma unroll
  for (int o = 1; o < 64; o <<= 1) {
    f0 += __shfl_xor(f0, o); f1 += __shfl_xor(f1, o);
    f2 += __shfl_xor(f2, o); f3 += __shfl_xor(f3, o);
  }
  x0 += f0 + bf2[0]; x1 += f1 + bf2[1]; x2 += f2 + bf2[2]; x3 += f3 + bf2[3];
  if (dofinal) {
    if (lane < NT_)
      out[tok * NT_ + lane] = bout[lane] + x0 * Wout[lane] + x1 * Wout[NT_ + lane] +
                              x2 * Wout[2 * NT_ + lane] + x3 * Wout[3 * NT_ + lane];
    return;
  }
  if (lane == 0) *(float4*)&x[tok * 4] = make_float4(x0, x1, x2, x3);
  if (doinln) {
    float xp[8];
    float s = 0.f, qs = 0.f;
#pragma unroll
    for (int k = 0; k < 8; k++) {
      int jj = 64 * k + lane;
      float v = bi[jj] + x0 * Wi[jj] + x1 * Wi[H_ + jj] + x2 * Wi[2 * H_ + jj] + x3 * Wi[3 * H_ + jj];
      xp[k] = v;
      s += v;
      qs += v * v;
    }
#pragma unroll
    for (int o = 1; o < 64; o <<= 1) {
      s += __shfl_xor(s, o);
      qs += __shfl_xor(qs, o);
    }
    float mean = s * (1.f / (float)H_);
    float var1 = qs * (1.f / (float)H_) - mean * mean;
    float rs1 = rsqrtf(var1 + EPS_);
#pragma unroll
    for (int k = 0; k < 8; k++) {
      int jj = 64 * k + lane;
      float v = (xp[k] - mean) * rs1 * g1[jj] + b1n[jj];
      xnbf[tok * H_ + jj] = bf16_rne(v);
    }
  }
}

extern "C" void kernel_launch(void* const* d_in, const int* in_sizes, int n_in,
                              void* d_out, int out_size, void* d_ws, size_t ws_size,
                              hipStream_t stream) {
  const int* patches = (const int*)d_in[0];
  const int* mask = (const int*)d_in[1];
  const float* emb = (const float*)d_in[2];
  const float* Wi = (const float*)d_in[3];
  const float* bi = (const float*)d_in[4];
  const float* Wqkv = (const float*)d_in[5];
  const float* bqkv = (const float*)d_in[6];
  const float* Wo = (const float*)d_in[7];
  const float* bo = (const float*)d_in[8];
  const float* g1 = (const float*)d_in[9];
  const float* b1n = (const float*)d_in[10];
  const float* Wf1 = (const float*)d_in[11];
  const float* bf1 = (const float*)d_in[12];
  const float* Wf2 = (const float*)d_in[13];
  const float* bf2 = (const float*)d_in[14];
  const float* g2 = (const float*)d_in[15];
  const float* b2n = (const float*)d_in[16];
  const float* relemb = (const float*)d_in[17];
  const float* Wout = (const float*)d_in[18];
  const float* bout = (const float*)d_in[19];
  float* out = (float*)d_out;

  char* p = (char*)d_ws;
  float* x = (float*)p;          p += (size_t)BS_ * 4 * 4;
  float* T = (float*)p;          p += (size_t)L_ * 2112 * 4;
  float* negT = (float*)p;       p += (size_t)BS_ * 4;
  float* AOp = (float*)p;        p += (size_t)KSPLIT_ * BS_ * NH_ * 4 * 4;
  float* lpart = (float*)p;      p += (size_t)KSPLIT_ * 32 * 1024 * 4;
  ushort* xnbf = (ushort*)p;     p += (size_t)BS_ * H_ * 2;
  ushort* Wt = (ushort*)p;       p += (size_t)L_ * 1536 * 512 * 2;
  ushort* qf = (ushort*)p;       p += (size_t)32 * 1024 * 64 * 2;
  ushort* kf = (ushort*)p;       p += (size_t)32 * 1024 * 64 * 2;
  ushort* vf = (ushort*)p;       p += (size_t)32 * 64 * 1024 * 2;

  k_pre<<<dim3(1841), dim3(256), 0, stream>>>(patches, mask, emb, relemb, Wqkv,
                                              Wi, bi, g1, b1n, x, T, negT, Wt, xnbf);
  for (int l = 0; l < L_; l++) {
    k_qkv<<<dim3(12, 32), dim3(512), 0, stream>>>(xnbf, Wt + (size_t)l * 1536 * 512,
                                                  bqkv + l * 3 * H_, qf, kf, vf);
    k_attn<<<dim3(1024), dim3(256), 0, stream>>>(qf, kf, vf, T + l * 2112, negT,
                                                 Wo + l * H_ * E_, AOp, lpart);
    int nl = l + 1;
    k_resffn<<<dim3(1024), dim3(256), 0, stream>>>(
        AOp, lpart, bo + l * E_, g2 + l * E_, b2n + l * E_,
        Wf1 + l * E_ * FF_, bf1 + l * FF_, Wf2 + l * FF_ * E_, bf2 + l * E_, x,
        Wi + nl * E_ * H_, bi + nl * H_, g1 + nl * H_, b1n + nl * H_, xnbf,
        (l < L_ - 1) ? 1 : 0, Wout, bout, out, (l == L_ - 1) ? 1 : 0);
  }
}

// Round 5
// 285.920 us; speedup vs baseline: 1.1642x; 1.0463x over previous
//
#include <hip/hip_runtime.h>
#include <hip/hip_bf16.h>
#include <math.h>

#define B_ 4
#define S_ 1024
#define H_ 512
#define NH_ 8
#define HD_ 64
#define FF_ 1024
#define E_ 4
#define L_ 4
#define NT_ 17
#define BS_ 4096
#define EPS_ 1e-5f
#define L2E_ 1.4426950408889634f
#define SCL_ 0.18033688011112042f   // 0.125 * log2(e)
#define KSPLIT_ 4

typedef __attribute__((ext_vector_type(8))) short short8;
typedef __attribute__((ext_vector_type(16))) float f32x16;
typedef float float4u __attribute__((ext_vector_type(4), aligned(4)));

__device__ inline ushort bf16_rne(float f) {
  unsigned u = __builtin_bit_cast(unsigned, f);
  u += 0x7FFFu + ((u >> 16) & 1u);
  return (ushort)(u >> 16);
}
__device__ inline unsigned pk_bf16(float a, float b) {
  return (unsigned)bf16_rne(a) | ((unsigned)bf16_rne(b) << 16);
}
// fast pack: round-half-away + v_perm_b32 (3 VALU ops)
__device__ inline unsigned pk2(float a, float b) {
  unsigned ua = __builtin_bit_cast(unsigned, a) + 0x8000u;
  unsigned ub = __builtin_bit_cast(unsigned, b) + 0x8000u;
  return __builtin_amdgcn_perm(ub, ua, 0x07060302u);
}
__device__ inline float ubf2f(ushort u) {
  return __builtin_bit_cast(float, ((unsigned)u) << 16);
}

// ===========================================================================
// Journal:
//  - R18/R19: full fusion (cooperative / software-barrier persistent kernel)
//    measured IDENTICAL to 13-launch => boundary overhead ~0; persistent
//    kernels also break rocprofv3 replay. 13-launch structure is final.
//  - R20 WIN: k_attn (256,3)->(256,4), JIT K/V loads: 332 -> 315.1.
//  - R21 WIN: k_qkv 8 waves/block (3 waves/SIMD): 315.1 -> 299.2.
//    Lens confirmed: latency/BW-bound at L2, fixes pay as modeled.
//  - R22: cut L2 traffic 4x via intra-block LDS reuse (same mechanism, two
//    kernels). k_attn: 4 waves/block read IDENTICAL K/V (same bh,j) but L1
//    (32KB) can't hold 4 blocks' working sets -> stage K+V tile (16KB/it)
//    cooperatively in LDS (2 barriers/it), LDS 34KB keeps 4 blocks/CU.
//    k_resffn: every wave re-read the same Wf1/bf1/Wf2 (36KB > L1) ->
//    stage once per block in LDS; 36KB = exactly 4 blocks/CU.
// ===========================================================================

// ---------------------------------------------------------------------------
// k_pre: fused one-time prologue (block-range dispatch).
//   bid in [0,768):     cvtw — Wqkv fp32 -> Wt bf16 [l][n][k] (LDS transpose)
//   bid in [768,817):   init — x/negT/T tables
//   bid in [817,1841):  inln layer 0 — wave/token, direct emb gather
// ---------------------------------------------------------------------------
__global__ __launch_bounds__(256) void k_pre(const int* __restrict__ patches,
                                             const int* __restrict__ mask,
                                             const float* __restrict__ emb,
                                             const float* __restrict__ relemb,
                                             const float* __restrict__ W,
                                             const float* __restrict__ Wi,
                                             const float* __restrict__ bi,
                                             const float* __restrict__ g1,
                                             const float* __restrict__ b1n,
                                             float* __restrict__ x,
                                             float* __restrict__ T,
                                             float* __restrict__ negT,
                                             ushort* __restrict__ Wt,
                                             ushort* __restrict__ xnbf) {
  __shared__ ushort Tr[64][72];
  int bid = blockIdx.x, t = threadIdx.x;
  if (bid < 768) {
    int l = bid / 192, rem = bid % 192;
    int k0 = (rem / 24) * 64, n0 = (rem % 24) * 64;
    const float* src = W + (size_t)l * 512 * 1536;
    int row = t >> 4, c4 = (t & 15) * 4;
#pragma unroll
    for (int rr = 0; rr < 4; rr++) {
      int k = rr * 16 + row;
      float4 v = *(const float4*)(src + (size_t)(k0 + k) * 1536 + n0 + c4);
      Tr[c4 + 0][k] = bf16_rne(v.x);
      Tr[c4 + 1][k] = bf16_rne(v.y);
      Tr[c4 + 2][k] = bf16_rne(v.z);
      Tr[c4 + 3][k] = bf16_rne(v.w);
    }
    __syncthreads();
    int nrow = t >> 2, kc = (t & 3) * 16;
    ushort* dst = Wt + ((size_t)(l * 1536 + n0 + nrow)) * 512 + k0 + kc;
    *(uint4*)dst = *(uint4*)&Tr[nrow][kc];
    *(uint4*)(dst + 8) = *(uint4*)&Tr[nrow][kc + 8];
  } else if (bid < 817) {
    int gid = (bid - 768) * 256 + t;
    if (gid < BS_) {
      int mk = mask[gid];
      int row = mk ? (NT_ - 1) : patches[gid];
      ((float4*)x)[gid] = ((const float4*)emb)[row];
      negT[gid] = mk ? -1e30f : 0.f;
    } else {
      int idx = gid - BS_;
      if (idx < L_ * 2112) {
        int l = idx / 2112, j = idx - l * 2112;
        int c = 1086 - j;
        c = c < 0 ? 0 : (c > 62 ? 62 : c);
        const float* src = relemb + (size_t)(l * 63 + c) * 64;
        float s = 0.f;
#pragma unroll
        for (int d = 0; d < 64; d++) s += src[d];
        T[idx] = s * L2E_;
      }
    }
  } else {
    int token = (bid - 817) * 4 + (t >> 6);
    int lane = t & 63;
    int mk = mask[token];
    int row = mk ? (NT_ - 1) : patches[token];
    float4 e = ((const float4*)emb)[row];
    float xp[8];
    float s = 0.f, qs = 0.f;
#pragma unroll
    for (int k = 0; k < 8; k++) {
      int jj = 64 * k + lane;
      float v = bi[jj] + e.x * Wi[jj] + e.y * Wi[H_ + jj] + e.z * Wi[2 * H_ + jj] + e.w * Wi[3 * H_ + jj];
      xp[k] = v; s += v; qs += v * v;
    }
#pragma unroll
    for (int o = 1; o < 64; o <<= 1) { s += __shfl_xor(s, o); qs += __shfl_xor(qs, o); }
    float mean = s * (1.f / (float)H_);
    float var = qs * (1.f / (float)H_) - mean * mean;
    float rs = rsqrtf(var + EPS_);
#pragma unroll
    for (int k = 0; k < 8; k++) {
      int jj = 64 * k + lane;
      xnbf[token * H_ + jj] = bf16_rne((xp[k] - mean) * rs * g1[jj] + b1n[jj]);
    }
  }
}

// ---------------------------------------------------------------------------
// k_qkv: bf16 MFMA GEMM; 128x128 tile, BK=64.  Register-prefetch + double-
// buffered LDS, one barrier per K-step.  R21: 8 waves/block (512 thr),
// wave grid 2Mx4N, 64x32 output per wave -> 3 waves/SIMD.
// ---------------------------------------------------------------------------
__global__ __launch_bounds__(512, 4) void k_qkv(const ushort* __restrict__ A,
                                                const ushort* __restrict__ Wt,
                                                const float* __restrict__ bias,
                                                ushort* __restrict__ qf,
                                                ushort* __restrict__ kf,
                                                ushort* __restrict__ vf) {
  __shared__ ushort At[2][128][72];
  __shared__ ushort Bt[2][128][72];
  int t = threadIdx.x;
  int n0 = blockIdx.x * 128, m0 = blockIdx.y * 128;
  bool tr = (n0 < 1024);
  int w = t >> 6, lq = t & 31, hh = (t >> 5) & 1;
  int wm = (w & 1) * 64, wn = (w >> 1) * 32;
  f32x16 acc[2];
#pragma unroll
  for (int mt = 0; mt < 2; mt++)
#pragma unroll
    for (int i = 0; i < 16; i++) acc[mt][i] = 0.f;

  uint4 ar[2], br[2];

#define QLOADREGS(k0_)                                                         \
  {                                                                            \
    _Pragma("unroll") for (int j = 0; j < 2; j++) {                            \
      int idl = 512 * j + t;                                                   \
      int row = idl >> 3, u = idl & 7;                                         \
      ar[j] = *(const uint4*)(A + (size_t)(m0 + row) * 512 + (k0_) + u * 8);   \
      br[j] = *(const uint4*)(Wt + (size_t)(n0 + row) * 512 + (k0_) + u * 8);  \
    }                                                                          \
  }
#define QWRITELDS(buf_)                                                        \
  {                                                                            \
    _Pragma("unroll") for (int j = 0; j < 2; j++) {                            \
      int idl = 512 * j + t;                                                   \
      int row = idl >> 3, u = idl & 7;                                         \
      *(uint4*)&At[buf_][row][u * 8] = ar[j];                                  \
      *(uint4*)&Bt[buf_][row][u * 8] = br[j];                                  \
    }                                                                          \
  }

  QLOADREGS(0);
  QWRITELDS(0);
  __syncthreads();

  for (int it = 0; it < 8; it++) {
    int buf = it & 1;
    if (it < 7) { QLOADREGS((it + 1) * 64); }
#pragma unroll
    for (int kc = 0; kc < 4; kc++) {
      short8 af[2], bf;
#pragma unroll
      for (int mt = 0; mt < 2; mt++) af[mt] = *(const short8*)&At[buf][wm + mt * 32 + lq][kc * 16 + hh * 8];
      bf = *(const short8*)&Bt[buf][wn + lq][kc * 16 + hh * 8];
#pragma unroll
      for (int mt = 0; mt < 2; mt++) {
        if (tr)
          acc[mt] = __builtin_amdgcn_mfma_f32_32x32x16_bf16(bf, af[mt], acc[mt], 0, 0, 0);
        else
          acc[mt] = __builtin_amdgcn_mfma_f32_32x32x16_bf16(af[mt], bf, acc[mt], 0, 0, 0);
      }
    }
    if (it < 7) {
      QWRITELDS(buf ^ 1);
      __syncthreads();
    }
  }
#undef QLOADREGS
#undef QWRITELDS

  if (tr) {
#pragma unroll
    for (int mt = 0; mt < 2; mt++) {
      int token = m0 + wm + mt * 32 + lq;
      int bb = token >> 10, sr = token & 1023;
      int qt = sr >> 5, lqp = sr & 31;
      int nn = n0 + wn;
      int nloc = (nn < 512) ? nn : nn - 512;
      ushort* dst = (nn < 512) ? qf : kf;
      int hd = nloc >> 6;
      int bh = bb * 8 + hd;
      size_t fragbase = ((size_t)(bh * 32 + qt)) * 4 * 512;
#pragma unroll
      for (int rg = 0; rg < 4; rg++) {
        int nbase = nn + rg * 8 + hh * 4;
        float4 bv = *(const float4*)(bias + nbase);
        float v0 = acc[mt][rg * 4 + 0] + bv.x;
        float v1 = acc[mt][rg * 4 + 1] + bv.y;
        float v2 = acc[mt][rg * 4 + 2] + bv.z;
        float v3 = acc[mt][rg * 4 + 3] + bv.w;
        int d0 = (nloc & 63) + rg * 8 + hh * 4;
        size_t addr = fragbase + (size_t)(d0 >> 4) * 512 +
                      (size_t)(((d0 >> 3) & 1) * 32 + lqp) * 8 + (d0 & 7);
        *(uint2*)(dst + addr) = make_uint2(pk_bf16(v0, v1), pk_bf16(v2, v3));
      }
    }
  } else {
    int n = n0 + wn + lq;
    int nloc = n - 1024;
    int hd = nloc >> 6, d = nloc & 63;
    float bb_ = bias[n];
#pragma unroll
    for (int mt = 0; mt < 2; mt++) {
#pragma unroll
      for (int rg = 0; rg < 4; rg++) {
        int tb = m0 + wm + mt * 32 + rg * 8 + hh * 4;
        int bb = tb >> 10, sr = tb & 1023;
        int bh = bb * 8 + hd;
        float v0 = acc[mt][rg * 4 + 0] + bb_;
        float v1 = acc[mt][rg * 4 + 1] + bb_;
        float v2 = acc[mt][rg * 4 + 2] + bb_;
        float v3 = acc[mt][rg * 4 + 3] + bb_;
        size_t addr = ((size_t)((bh * 2 + (d >> 5)) * 64 + (sr >> 4))) * 512 +
                      (size_t)(((sr >> 3) & 1) * 32 + (d & 31)) * 8 + (sr & 7);
        *(uint2*)(vf + addr) = make_uint2(pk_bf16(v0, v1), pk_bf16(v2, v3));
      }
    }
  }
}

// ---------------------------------------------------------------------------
// k_attn: bf16 MFMA attention, S^T form, fixed-scale softmax.
// R20: (256,4), 1024 blocks = one full round, 4 waves/SIMD.
// R22: K/V staged in LDS per it (4 waves of a block read identical chunks;
// staging is 4x256 coalesced uint4, 2 barriers/it).  L2 traffic /4.
// LDS: Kl 8KB + Vl 8KB + Pt 18KB = 34KB -> still 4 blocks/CU.
// ---------------------------------------------------------------------------
__global__ __launch_bounds__(256, 4) void k_attn(const ushort* __restrict__ qf,
                                                 const ushort* __restrict__ kf,
                                                 const ushort* __restrict__ vf,
                                                 const float* __restrict__ Tl,
                                                 const float* __restrict__ negT,
                                                 const float* __restrict__ Wol,
                                                 float* __restrict__ AOp,
                                                 float* __restrict__ lpart) {
  __shared__ ushort Kl[2][2048];   // 8 KB (st-major copy of global chunk)
  __shared__ ushort Vl[2][2048];   // 8 KB (dt-major)
  __shared__ ushort Pt[4][32][72]; // 18 KB
  int t = threadIdx.x;
  int w = t >> 6, lane = t & 63;
  int lq = lane & 31, hh = lane >> 5;
  int id = blockIdx.x;
  int bh = id & 31;
  int slot = id >> 5;
  int qtg = slot & 7, j = slot >> 3;
  int b = bh >> 3, head = bh & 7;
  int qt = qtg * 4 + w;
  int q = qt * 32 + lq;
  int kstart = j * 256;

  const ushort* qbase = qf + ((size_t)(bh * 32 + qt)) * 2048 + lane * 8;
  short8 Qf[4];
#pragma unroll
  for (int c = 0; c < 4; c++) Qf[c] = *(const short8*)(qbase + c * 512);

  float Tlo = Tl[1086];
  float Thi = Tl[1024];

  float l_run = 0.f;
  f32x16 Ot[2];
#pragma unroll
  for (int dt = 0; dt < 2; dt++)
#pragma unroll
    for (int i = 0; i < 16; i++) Ot[dt][i] = 0.f;

  for (int it = 0; it < 4; it++) {
    int k0 = kstart + it * 64;
    // ---- cooperative stage of K+V tile (16KB, 4x256 coalesced uint4) ----
    {
      const uint4* ks0 = (const uint4*)(kf + ((size_t)(bh * 32 + (k0 >> 5) + 0)) * 2048);
      const uint4* ks1 = (const uint4*)(kf + ((size_t)(bh * 32 + (k0 >> 5) + 1)) * 2048);
      const uint4* vs0 = (const uint4*)(vf + ((size_t)((bh * 2 + 0) * 64 + (k0 >> 4))) * 512);
      const uint4* vs1 = (const uint4*)(vf + ((size_t)((bh * 2 + 1) * 64 + (k0 >> 4))) * 512);
      ((uint4*)Kl[0])[t] = ks0[t];
      ((uint4*)Kl[1])[t] = ks1[t];
      ((uint4*)Vl[0])[t] = vs0[t];
      ((uint4*)Vl[1])[t] = vs1[t];
    }
    __syncthreads();
    // ---- per-st: K frag from LDS, S^T MFMA, softmax ----
#pragma unroll
    for (int st = 0; st < 2; st++) {
      short8 Kb[4];
#pragma unroll
      for (int c = 0; c < 4; c++) Kb[c] = *(const short8*)&Kl[st][lane * 8 + c * 512];
      f32x16 sa;
#pragma unroll
      for (int i = 0; i < 16; i++) sa[i] = 0.f;
#pragma unroll
      for (int c = 0; c < 4; c++)
        sa = __builtin_amdgcn_mfma_f32_32x32x16_bf16(Kb[c], Qf[c], sa, 0, 0, 0);
      int kt0 = k0 + st * 32;
      int delta = kt0 - qt * 32;
      if (delta >= 64 || delta <= -64) {
        float bconst = (delta >= 64) ? Tlo : Thi;
#pragma unroll
        for (int rg = 0; rg < 4; rg++) {
          int krun = kt0 + rg * 8 + hh * 4;
          float4 nv = *(const float4*)(negT + b * S_ + krun);
          float p0 = exp2f(fmaf(sa[rg * 4 + 0], SCL_, bconst + nv.x));
          float p1 = exp2f(fmaf(sa[rg * 4 + 1], SCL_, bconst + nv.y));
          float p2 = exp2f(fmaf(sa[rg * 4 + 2], SCL_, bconst + nv.z));
          float p3 = exp2f(fmaf(sa[rg * 4 + 3], SCL_, bconst + nv.w));
          l_run += (p0 + p1) + (p2 + p3);
          *(uint2*)&Pt[w][lq][st * 32 + rg * 8 + hh * 4] = make_uint2(pk2(p0, p1), pk2(p2, p3));
        }
      } else {
#pragma unroll
        for (int rg = 0; rg < 4; rg++) {
          int krun = kt0 + rg * 8 + hh * 4;
          float4u bv = *(const float4u*)(Tl + (krun - q + 31 + 1024));
          float4 nv = *(const float4*)(negT + b * S_ + krun);
          float pp[4];
#pragma unroll
          for (int i = 0; i < 4; i++) {
            float nvi = (i == 0) ? nv.x : (i == 1) ? nv.y : (i == 2) ? nv.z : nv.w;
            float t0 = (krun + i == q) ? bv[i] : (bv[i] + nvi);
            pp[i] = exp2f(fmaf(sa[rg * 4 + i], SCL_, t0));
            l_run += pp[i];
          }
          *(uint2*)&Pt[w][lq][st * 32 + rg * 8 + hh * 4] = make_uint2(pk2(pp[0], pp[1]), pk2(pp[2], pp[3]));
        }
      }
    }
    // ---- O^T += V^T . P  (V frags from LDS) ----
    short8 Pf[4];
#pragma unroll
    for (int c = 0; c < 4; c++) Pf[c] = *(const short8*)&Pt[w][lq][c * 16 + hh * 8];
#pragma unroll
    for (int dt = 0; dt < 2; dt++) {
      short8 Vb[4];
#pragma unroll
      for (int c = 0; c < 4; c++) Vb[c] = *(const short8*)&Vl[dt][lane * 8 + c * 512];
#pragma unroll
      for (int c = 0; c < 4; c++)
        Ot[dt] = __builtin_amdgcn_mfma_f32_32x32x16_bf16(Vb[c], Pf[c], Ot[dt], 0, 0, 0);
    }
    __syncthreads();  // protect Kl/Vl before next stage
  }
  // ---- epilogue: project through Wo[head], store private j-slot partial ----
  const float* woh = Wol + head * 64 * 4;
  float pe0 = 0.f, pe1 = 0.f, pe2 = 0.f, pe3 = 0.f;
#pragma unroll
  for (int dt = 0; dt < 2; dt++)
#pragma unroll
    for (int rg = 0; rg < 4; rg++)
#pragma unroll
      for (int i = 0; i < 4; i++) {
        int d = dt * 32 + rg * 8 + hh * 4 + i;
        float4 wv = *(const float4*)(woh + d * 4);
        float o = Ot[dt][rg * 4 + i];
        pe0 = fmaf(o, wv.x, pe0);
        pe1 = fmaf(o, wv.y, pe1);
        pe2 = fmaf(o, wv.z, pe2);
        pe3 = fmaf(o, wv.w, pe3);
      }
  pe0 += __shfl_xor(pe0, 32);
  pe1 += __shfl_xor(pe1, 32);
  pe2 += __shfl_xor(pe2, 32);
  pe3 += __shfl_xor(pe3, 32);
  float l_tot = l_run + __shfl_xor(l_run, 32);
  if (hh == 0) {
    float* ao = AOp + (size_t)j * (BS_ * NH_ * 4) + ((size_t)(b * S_ + q) * NH_ + head) * 4;
    *(float4*)ao = make_float4(pe0, pe1, pe2, pe3);
    lpart[((size_t)j * 32 + bh) * S_ + q] = l_tot;
  }
}

// ---------------------------------------------------------------------------
// k_resffn: combine j-slot partials per head, sum heads, x += ao + bo,
// ln2(E=4), FFN, residual.  doinln: fuse next layer's inproj+LN.
// R22: Wf1/bf1/Wf2 (36KB) staged once per block in LDS (shared by 4 waves,
// was re-read from L2 by all 4096 waves).  36KB -> exactly 4 blocks/CU.
// ---------------------------------------------------------------------------
__global__ __launch_bounds__(256, 4) void k_resffn(const float* __restrict__ AOp,
                                                const float* __restrict__ lpart,
                                                const float* __restrict__ bo,
                                                const float* __restrict__ g2,
                                                const float* __restrict__ b2n,
                                                const float* __restrict__ Wf1,
                                                const float* __restrict__ bf1,
                                                const float* __restrict__ Wf2,
                                                const float* __restrict__ bf2,
                                                float* __restrict__ x,
                                                const float* __restrict__ Wi,
                                                const float* __restrict__ bi,
                                                const float* __restrict__ g1,
                                                const float* __restrict__ b1n,
                                                ushort* __restrict__ xnbf,
                                                int doinln,
                                                const float* __restrict__ Wout,
                                                const float* __restrict__ bout,
                                                float* __restrict__ out,
                                                int dofinal) {
  __shared__ float Wf1s[4096];   // 16 KB
  __shared__ float bf1s[1024];   // 4 KB
  __shared__ float Wf2s[4096];   // 16 KB
  int t = threadIdx.x;
#pragma unroll
  for (int i = 0; i < 4; i++) ((float4*)Wf1s)[i * 256 + t] = ((const float4*)Wf1)[i * 256 + t];
  ((float4*)bf1s)[t] = ((const float4*)bf1)[t];
#pragma unroll
  for (int i = 0; i < 4; i++) ((float4*)Wf2s)[i * 256 + t] = ((const float4*)Wf2)[i * 256 + t];

  int tok = blockIdx.x * 4 + (t >> 6);
  int lane = t & 63;
  int b = tok >> 10, qq = tok & 1023;
  int h = lane & 7;
  int lidx = (b * 8 + h) * 1024 + qq;
  float ls = lpart[lidx] + lpart[lidx + 32768] + lpart[lidx + 65536] + lpart[lidx + 98304];
  float inv = 1.f / ls;
  size_t abase = ((size_t)tok * 8 + h) * 4;
  float4 v0 = *(const float4*)(AOp + abase);
  float4 v1 = *(const float4*)(AOp + abase + 131072);
  float4 v2 = *(const float4*)(AOp + abase + 262144);
  float4 v3 = *(const float4*)(AOp + abase + 393216);
  float r0 = (v0.x + v1.x + v2.x + v3.x) * inv;
  float r1 = (v0.y + v1.y + v2.y + v3.y) * inv;
  float r2 = (v0.z + v1.z + v2.z + v3.z) * inv;
  float r3 = (v0.w + v1.w + v2.w + v3.w) * inv;
#pragma unroll
  for (int o = 1; o < 8; o <<= 1) {
    r0 += __shfl_xor(r0, o); r1 += __shfl_xor(r1, o);
    r2 += __shfl_xor(r2, o); r3 += __shfl_xor(r3, o);
  }
  float4 xo = *(const float4*)&x[tok * 4];
  float x0 = xo.x + r0 + bo[0];
  float x1 = xo.y + r1 + bo[1];
  float x2 = xo.z + r2 + bo[2];
  float x3 = xo.w + r3 + bo[3];
  float mn = 0.25f * (x0 + x1 + x2 + x3);
  float d0 = x0 - mn, d1 = x1 - mn, d2 = x2 - mn, d3 = x3 - mn;
  float var = 0.25f * (d0 * d0 + d1 * d1 + d2 * d2 + d3 * d3);
  float rs = rsqrtf(var + EPS_);
  float l0 = d0 * rs * g2[0] + b2n[0];
  float l1 = d1 * rs * g2[1] + b2n[1];
  float l2 = d2 * rs * g2[2] + b2n[2];
  float l3 = d3 * rs * g2[3] + b2n[3];
  __syncthreads();  // Wf1s/bf1s/Wf2s ready
  float f0 = 0, f1 = 0, f2 = 0, f3 = 0;
#pragma unroll
  for (int f4 = 0; f4 < FF_ / 64; f4++) {
    int f = lane + f4 * 64;
    float hh = bf1s[f] + l0 * Wf1s[f] + l1 * Wf1s[FF_ + f] + l2 * Wf1s[2 * FF_ + f] + l3 * Wf1s[3 * FF_ + f];
    hh = fmaxf(hh, 0.f);
    float4 w2 = *(const float4*)&Wf2s[f * 4];
    f0 += hh * w2.x; f1 += hh * w2.y; f2 += hh * w2.z; f3 += hh * w2.w;
  }
#pragma unroll
  for (int o = 1; o < 64; o <<= 1) {
    f0 += __shfl_xor(f0, o); f1 += __shfl_xor(f1, o);
    f2 += __shfl_xor(f2, o); f3 += __shfl_xor(f3, o);
  }
  x0 += f0 + bf2[0]; x1 += f1 + bf2[1]; x2 += f2 + bf2[2]; x3 += f3 + bf2[3];
  if (dofinal) {
    if (lane < NT_)
      out[tok * NT_ + lane] = bout[lane] + x0 * Wout[lane] + x1 * Wout[NT_ + lane] +
                              x2 * Wout[2 * NT_ + lane] + x3 * Wout[3 * NT_ + lane];
    return;
  }
  if (lane == 0) *(float4*)&x[tok * 4] = make_float4(x0, x1, x2, x3);
  if (doinln) {
    float xp[8];
    float s = 0.f, qs = 0.f;
#pragma unroll
    for (int k = 0; k < 8; k++) {
      int jj = 64 * k + lane;
      float v = bi[jj] + x0 * Wi[jj] + x1 * Wi[H_ + jj] + x2 * Wi[2 * H_ + jj] + x3 * Wi[3 * H_ + jj];
      xp[k] = v;
      s += v;
      qs += v * v;
    }
#pragma unroll
    for (int o = 1; o < 64; o <<= 1) {
      s += __shfl_xor(s, o);
      qs += __shfl_xor(qs, o);
    }
    float mean = s * (1.f / (float)H_);
    float var1 = qs * (1.f / (float)H_) - mean * mean;
    float rs1 = rsqrtf(var1 + EPS_);
#pragma unroll
    for (int k = 0; k < 8; k++) {
      int jj = 64 * k + lane;
      float v = (xp[k] - mean) * rs1 * g1[jj] + b1n[jj];
      xnbf[tok * H_ + jj] = bf16_rne(v);
    }
  }
}

extern "C" void kernel_launch(void* const* d_in, const int* in_sizes, int n_in,
                              void* d_out, int out_size, void* d_ws, size_t ws_size,
                              hipStream_t stream) {
  const int* patches = (const int*)d_in[0];
  const int* mask = (const int*)d_in[1];
  const float* emb = (const float*)d_in[2];
  const float* Wi = (const float*)d_in[3];
  const float* bi = (const float*)d_in[4];
  const float* Wqkv = (const float*)d_in[5];
  const float* bqkv = (const float*)d_in[6];
  const float* Wo = (const float*)d_in[7];
  const float* bo = (const float*)d_in[8];
  const float* g1 = (const float*)d_in[9];
  const float* b1n = (const float*)d_in[10];
  const float* Wf1 = (const float*)d_in[11];
  const float* bf1 = (const float*)d_in[12];
  const float* Wf2 = (const float*)d_in[13];
  const float* bf2 = (const float*)d_in[14];
  const float* g2 = (const float*)d_in[15];
  const float* b2n = (const float*)d_in[16];
  const float* relemb = (const float*)d_in[17];
  const float* Wout = (const float*)d_in[18];
  const float* bout = (const float*)d_in[19];
  float* out = (float*)d_out;

  char* p = (char*)d_ws;
  float* x = (float*)p;          p += (size_t)BS_ * 4 * 4;
  float* T = (float*)p;          p += (size_t)L_ * 2112 * 4;
  float* negT = (float*)p;       p += (size_t)BS_ * 4;
  float* AOp = (float*)p;        p += (size_t)KSPLIT_ * BS_ * NH_ * 4 * 4;
  float* lpart = (float*)p;      p += (size_t)KSPLIT_ * 32 * 1024 * 4;
  ushort* xnbf = (ushort*)p;     p += (size_t)BS_ * H_ * 2;
  ushort* Wt = (ushort*)p;       p += (size_t)L_ * 1536 * 512 * 2;
  ushort* qf = (ushort*)p;       p += (size_t)32 * 1024 * 64 * 2;
  ushort* kf = (ushort*)p;       p += (size_t)32 * 1024 * 64 * 2;
  ushort* vf = (ushort*)p;       p += (size_t)32 * 64 * 1024 * 2;

  k_pre<<<dim3(1841), dim3(256), 0, stream>>>(patches, mask, emb, relemb, Wqkv,
                                              Wi, bi, g1, b1n, x, T, negT, Wt, xnbf);
  for (int l = 0; l < L_; l++) {
    k_qkv<<<dim3(12, 32), dim3(512), 0, stream>>>(xnbf, Wt + (size_t)l * 1536 * 512,
                                                  bqkv + l * 3 * H_, qf, kf, vf);
    k_attn<<<dim3(1024), dim3(256), 0, stream>>>(qf, kf, vf, T + l * 2112, negT,
                                                 Wo + l * H_ * E_, AOp, lpart);
    int nl = l + 1;
    k_resffn<<<dim3(1024), dim3(256), 0, stream>>>(
        AOp, lpart, bo + l * E_, g2 + l * E_, b2n + l * E_,
        Wf1 + l * E_ * FF_, bf1 + l * FF_, Wf2 + l * FF_ * E_, bf2 + l * E_, x,
        Wi + nl * E_ * H_, bi + nl * H_, g1 + nl * H_, b1n + nl * H_, xnbf,
        (l < L_ - 1) ? 1 : 0, Wout, bout, out, (l == L_ - 1) ? 1 : 0);
  }
}